// Round 1
// baseline (1507.959 us; speedup 1.0000x reference)
//
#include <hip/hip_runtime.h>
#include <math.h>

// SHSA fused block, fp32 baseline (round 1: correctness + decent tiling).
// Pipeline: stats -> finalize -> qk -> v-GEMM -> attn stats -> attn PV -> proj GEMM.

namespace {
constexpr int BATCH = 8;
constexpr int CDIM  = 512;
constexpr int PD    = 256;       // PDIM
constexpr int NPIX  = 4096;     // H*W
constexpr int NTOT  = PD * NPIX; // elements per batch for GN stats

// workspace layout (float offsets)
constexpr int OFF_PART = 0;                            // 8*64*2
constexpr int OFF_STAT = 2048;                         // 8*2 (mean,rstd)
constexpr int OFF_QK   = 4096;                         // 8*32*4096
constexpr int OFF_V    = OFF_QK + BATCH * 32 * NPIX;   // 8*256*4096
constexpr int OFF_M    = OFF_V + BATCH * PD * NPIX;    // 8*4096
constexpr int OFF_L    = OFF_M + BATCH * NPIX;         // 8*4096
constexpr int OFF_X1O  = OFF_L + BATCH * NPIX;         // 8*256*4096
} // namespace

// ---------------- K1a: per-chunk partial sums for GroupNorm stats ----------
__global__ __launch_bounds__(256) void k_stats_partial(const float* __restrict__ x,
                                                       float* __restrict__ ws) {
    int b = blockIdx.y, chunk = blockIdx.x, t = threadIdx.x;
    const float4* x4 = reinterpret_cast<const float4*>(
        x + (size_t)b * CDIM * NPIX + (size_t)chunk * 16384);
    float s = 0.f, sq = 0.f;
#pragma unroll
    for (int i = 0; i < 16; ++i) {
        float4 v = x4[i * 256 + t];
        s  += v.x + v.y + v.z + v.w;
        sq += v.x * v.x + v.y * v.y + v.z * v.z + v.w * v.w;
    }
    for (int off = 32; off; off >>= 1) {
        s  += __shfl_down(s, off);
        sq += __shfl_down(sq, off);
    }
    __shared__ float red[8];
    int wid = t >> 6, lane = t & 63;
    if (lane == 0) { red[wid * 2] = s; red[wid * 2 + 1] = sq; }
    __syncthreads();
    if (t == 0) {
        float S = red[0] + red[2] + red[4] + red[6];
        float Q = red[1] + red[3] + red[5] + red[7];
        ws[OFF_PART + (b * 64 + chunk) * 2]     = S;
        ws[OFF_PART + (b * 64 + chunk) * 2 + 1] = Q;
    }
}

// ---------------- K1b: finalize mean / rstd per batch ----------------------
__global__ __launch_bounds__(64) void k_stats_final(float* __restrict__ ws) {
    int b = blockIdx.x, t = threadIdx.x; // 64 threads
    float s = ws[OFF_PART + (b * 64 + t) * 2];
    float q = ws[OFF_PART + (b * 64 + t) * 2 + 1];
    for (int off = 32; off; off >>= 1) {
        s += __shfl_down(s, off);
        q += __shfl_down(q, off);
    }
    if (t == 0) {
        float mean = s / (float)NTOT;
        float var  = q / (float)NTOT - mean * mean;
        ws[OFF_STAT + b * 2]     = mean;
        ws[OFF_STAT + b * 2 + 1] = rsqrtf(var + 1e-5f);
    }
}

// ---------------- K2a: q,k rows (32 x 4096 per batch) ----------------------
__global__ __launch_bounds__(256) void k_qk(const float* __restrict__ x,
                                            const float* __restrict__ gnw,
                                            const float* __restrict__ gnb,
                                            const float* __restrict__ wqkv,
                                            const float* __restrict__ bqkv,
                                            float* __restrict__ ws) {
    int b = blockIdx.y, n0 = blockIdx.x * 64, t = threadIdx.x;
    int o = t & 31, ng = t >> 5; // ng < 8
    float mu = ws[OFF_STAT + b * 2], rs = ws[OFF_STAT + b * 2 + 1];
    const float* xb = x + (size_t)b * CDIM * NPIX;
    float acc[8];
    float bias = bqkv[o];
#pragma unroll
    for (int i = 0; i < 8; ++i) acc[i] = bias;
    for (int c = 0; c < PD; ++c) {
        float w = wqkv[o * PD + c];
        float a = rs * gnw[c];
        float sh = gnb[c] - mu * a;
        const float* xr = xb + (size_t)c * NPIX + n0;
#pragma unroll
        for (int i = 0; i < 8; ++i) {
            float xv = xr[ng + 8 * i];
            acc[i] += w * (xv * a + sh);
        }
    }
    float* qk = ws + OFF_QK + (size_t)b * 32 * NPIX + (size_t)o * NPIX + n0;
#pragma unroll
    for (int i = 0; i < 8; ++i) qk[ng + 8 * i] = acc[i];
}

// ---------------- K2b: v = w_v @ x1n + b_v  (256x256x4096 per batch) -------
__global__ __launch_bounds__(256) void k_vgemm(const float* __restrict__ x,
                                               const float* __restrict__ gnw,
                                               const float* __restrict__ gnb,
                                               const float* __restrict__ wqkv,
                                               const float* __restrict__ bqkv,
                                               float* __restrict__ ws) {
    int b = blockIdx.z, n0 = blockIdx.x * 128, m0 = blockIdx.y * 128;
    int t = threadIdx.x;
    float mu = ws[OFF_STAT + b * 2], rs = ws[OFF_STAT + b * 2 + 1];
    __shared__ float As[32][132];
    __shared__ float Bs[32][132];
    float acc[8][8];
#pragma unroll
    for (int i = 0; i < 8; ++i)
#pragma unroll
        for (int j = 0; j < 8; ++j) acc[i][j] = 0.f;
    const float* xb = x + (size_t)b * CDIM * NPIX;
    int tm = t >> 4, tn = t & 15;

    for (int k0 = 0; k0 < PD; k0 += 32) {
        // A tile: w_v[m0+row][k0+kk], transposed into As[k][row]
        {
            int kk = (t & 7) * 4;
            int rbase = t >> 3; // 0..31
#pragma unroll
            for (int p = 0; p < 4; ++p) {
                int row = p * 32 + rbase;
                float4 a4 = *reinterpret_cast<const float4*>(
                    wqkv + (size_t)(32 + m0 + row) * PD + k0 + kk);
                As[kk + 0][row] = a4.x; As[kk + 1][row] = a4.y;
                As[kk + 2][row] = a4.z; As[kk + 3][row] = a4.w;
            }
        }
        // B tile: x1n[k0+k][n0+nn] (GroupNorm applied on the fly)
        {
            int nf = (t & 31) * 4;
            int kb = t >> 5; // 0..7
#pragma unroll
            for (int p = 0; p < 4; ++p) {
                int k = p * 8 + kb;
                int c = k0 + k;
                float a = rs * gnw[c];
                float sh = gnb[c] - mu * a;
                float4 v4 = *reinterpret_cast<const float4*>(xb + (size_t)c * NPIX + n0 + nf);
                float4 o4 = make_float4(v4.x * a + sh, v4.y * a + sh,
                                        v4.z * a + sh, v4.w * a + sh);
                *reinterpret_cast<float4*>(&Bs[k][nf]) = o4;
            }
        }
        __syncthreads();
#pragma unroll 2
        for (int k = 0; k < 32; ++k) {
            float4 a0 = *reinterpret_cast<const float4*>(&As[k][tm * 8]);
            float4 a1 = *reinterpret_cast<const float4*>(&As[k][tm * 8 + 4]);
            float4 b0 = *reinterpret_cast<const float4*>(&Bs[k][tn * 8]);
            float4 b1 = *reinterpret_cast<const float4*>(&Bs[k][tn * 8 + 4]);
            float av[8] = {a0.x, a0.y, a0.z, a0.w, a1.x, a1.y, a1.z, a1.w};
            float bv[8] = {b0.x, b0.y, b0.z, b0.w, b1.x, b1.y, b1.z, b1.w};
#pragma unroll
            for (int i = 0; i < 8; ++i)
#pragma unroll
                for (int j = 0; j < 8; ++j) acc[i][j] += av[i] * bv[j];
        }
        __syncthreads();
    }
    float* vout = ws + OFF_V + (size_t)b * PD * NPIX;
#pragma unroll
    for (int i = 0; i < 8; ++i) {
        int c = m0 + tm * 8 + i;
        float bb = bqkv[32 + c];
        float4 r0 = make_float4(acc[i][0] + bb, acc[i][1] + bb, acc[i][2] + bb, acc[i][3] + bb);
        float4 r1 = make_float4(acc[i][4] + bb, acc[i][5] + bb, acc[i][6] + bb, acc[i][7] + bb);
        *reinterpret_cast<float4*>(vout + (size_t)c * NPIX + n0 + tn * 8)     = r0;
        *reinterpret_cast<float4*>(vout + (size_t)c * NPIX + n0 + tn * 8 + 4) = r1;
    }
}

// ---------------- K3a: softmax row max M and denom L -----------------------
__global__ __launch_bounds__(256) void k_attn_stats(float* __restrict__ ws) {
    int b = blockIdx.y, q0 = blockIdx.x * 64, t = threadIdx.x;
    __shared__ float Q[16][64];
    __shared__ float K[16][64];
    const float* qk = ws + OFF_QK + (size_t)b * 32 * NPIX;
    {
        int d = t >> 4, f = (t & 15) * 4;
        *reinterpret_cast<float4*>(&Q[d][f]) =
            *reinterpret_cast<const float4*>(qk + (size_t)d * NPIX + q0 + f);
    }
    int nq = t >> 2, g = t & 3;
    float mrun = -1e30f, lrun = 0.f;
    for (int m0 = 0; m0 < NPIX; m0 += 64) {
        __syncthreads();
        {
            int d = t >> 4, f = (t & 15) * 4;
            *reinterpret_cast<float4*>(&K[d][f]) =
                *reinterpret_cast<const float4*>(qk + (size_t)(16 + d) * NPIX + m0 + f);
        }
        __syncthreads();
        float s[16];
#pragma unroll
        for (int i = 0; i < 16; ++i) s[i] = 0.f;
#pragma unroll
        for (int d = 0; d < 16; ++d) {
            float qd = Q[d][nq];
            float4 k0v = *reinterpret_cast<const float4*>(&K[d][g * 16]);
            float4 k1v = *reinterpret_cast<const float4*>(&K[d][g * 16 + 4]);
            float4 k2v = *reinterpret_cast<const float4*>(&K[d][g * 16 + 8]);
            float4 k3v = *reinterpret_cast<const float4*>(&K[d][g * 16 + 12]);
            float kk[16] = {k0v.x, k0v.y, k0v.z, k0v.w, k1v.x, k1v.y, k1v.z, k1v.w,
                            k2v.x, k2v.y, k2v.z, k2v.w, k3v.x, k3v.y, k3v.z, k3v.w};
#pragma unroll
            for (int i = 0; i < 16; ++i) s[i] += qd * kk[i];
        }
        float tmax = -1e30f;
#pragma unroll
        for (int i = 0; i < 16; ++i) { s[i] *= 0.25f; tmax = fmaxf(tmax, s[i]); }
        float mnew = fmaxf(mrun, tmax);
        float sum = 0.f;
#pragma unroll
        for (int i = 0; i < 16; ++i) sum += __expf(s[i] - mnew);
        lrun = lrun * __expf(mrun - mnew) + sum;
        mrun = mnew;
    }
    // combine the 4 lanes sharing one query row
#pragma unroll
    for (int off = 1; off <= 2; off <<= 1) {
        float mo = __shfl_xor(mrun, off);
        float lo = __shfl_xor(lrun, off);
        float mnew = fmaxf(mrun, mo);
        lrun = lrun * __expf(mrun - mnew) + lo * __expf(mo - mnew);
        mrun = mnew;
    }
    if (g == 0) {
        ws[OFF_M + b * NPIX + q0 + nq] = mrun;
        ws[OFF_L + b * NPIX + q0 + nq] = lrun;
    }
}

// ---------------- K3b: PV pass: x1o[c][n] = (1/L) sum_m exp(s-M) v[c][m] ---
__global__ __launch_bounds__(512) void k_attn_pv(float* __restrict__ ws) {
    int b = blockIdx.y, q0 = blockIdx.x * 128, t = threadIdx.x;
    __shared__ float Q[16][128];
    __shared__ float Kt[16][32];
    __shared__ float P[128][33];
    __shared__ float V[32][260];
    __shared__ float Mr[128];
    __shared__ float Lr[128];
    const float* qk = ws + OFF_QK + (size_t)b * 32 * NPIX;
    const float* vg = ws + OFF_V + (size_t)b * PD * NPIX;
    {
        int d = t >> 5, f = (t & 31) * 4;
        *reinterpret_cast<float4*>(&Q[d][f]) =
            *reinterpret_cast<const float4*>(qk + (size_t)d * NPIX + q0 + f);
    }
    if (t < 128) {
        Mr[t] = ws[OFF_M + b * NPIX + q0 + t];
        Lr[t] = ws[OFF_L + b * NPIX + q0 + t];
    }
    int rg = t & 31, cg = t >> 5; // cg < 16
    float acc[4][16];
#pragma unroll
    for (int i = 0; i < 4; ++i)
#pragma unroll
        for (int j = 0; j < 16; ++j) acc[i][j] = 0.f;

    for (int m0 = 0; m0 < NPIX; m0 += 32) {
        __syncthreads();
        if (t < 128) { // K tile 16x32
            int d = t >> 3, f = (t & 7) * 4;
            *reinterpret_cast<float4*>(&Kt[d][f]) =
                *reinterpret_cast<const float4*>(qk + (size_t)(16 + d) * NPIX + m0 + f);
        }
        // V tile 32m x 256c, transposed to V[m][c]
#pragma unroll
        for (int p = 0; p < 4; ++p) {
            int c = p * 64 + (t >> 3), f4 = t & 7;
            float4 v4 = *reinterpret_cast<const float4*>(vg + (size_t)c * NPIX + m0 + f4 * 4);
            V[f4 * 4 + 0][c] = v4.x; V[f4 * 4 + 1][c] = v4.y;
            V[f4 * 4 + 2][c] = v4.z; V[f4 * 4 + 3][c] = v4.w;
        }
        __syncthreads();
        // scores + P for this tile: 8 per thread
        {
            int snq = t >> 2, sg = t & 3;
            float s[8] = {0.f, 0.f, 0.f, 0.f, 0.f, 0.f, 0.f, 0.f};
#pragma unroll
            for (int d = 0; d < 16; ++d) {
                float qd = Q[d][snq];
                float4 ka = *reinterpret_cast<const float4*>(&Kt[d][sg * 8]);
                float4 kb = *reinterpret_cast<const float4*>(&Kt[d][sg * 8 + 4]);
                s[0] += qd * ka.x; s[1] += qd * ka.y; s[2] += qd * ka.z; s[3] += qd * ka.w;
                s[4] += qd * kb.x; s[5] += qd * kb.y; s[6] += qd * kb.z; s[7] += qd * kb.w;
            }
            float mm = Mr[snq];
#pragma unroll
            for (int i = 0; i < 8; ++i) P[snq][sg * 8 + i] = __expf(s[i] * 0.25f - mm);
        }
        __syncthreads();
        // PV accumulate
#pragma unroll 2
        for (int m = 0; m < 32; ++m) {
            float p0 = P[rg][m], p1 = P[rg + 32][m], p2 = P[rg + 64][m], p3 = P[rg + 96][m];
            float4 v0 = *reinterpret_cast<const float4*>(&V[m][cg * 16]);
            float4 v1 = *reinterpret_cast<const float4*>(&V[m][cg * 16 + 4]);
            float4 v2 = *reinterpret_cast<const float4*>(&V[m][cg * 16 + 8]);
            float4 v3 = *reinterpret_cast<const float4*>(&V[m][cg * 16 + 12]);
            float vv[16] = {v0.x, v0.y, v0.z, v0.w, v1.x, v1.y, v1.z, v1.w,
                            v2.x, v2.y, v2.z, v2.w, v3.x, v3.y, v3.z, v3.w};
#pragma unroll
            for (int j = 0; j < 16; ++j) {
                acc[0][j] += p0 * vv[j];
                acc[1][j] += p1 * vv[j];
                acc[2][j] += p2 * vv[j];
                acc[3][j] += p3 * vv[j];
            }
        }
    }
    float* x1o = ws + OFF_X1O + (size_t)b * PD * NPIX;
    float invl[4];
#pragma unroll
    for (int i = 0; i < 4; ++i) invl[i] = 1.f / Lr[rg + 32 * i];
#pragma unroll
    for (int j = 0; j < 16; ++j) {
        int c = cg * 16 + j;
#pragma unroll
        for (int i = 0; i < 4; ++i) {
            x1o[(size_t)c * NPIX + q0 + rg + 32 * i] = acc[i][j] * invl[i];
        }
    }
}

// ---------------- K4: out = w_proj @ silu(concat(x1o, x2)) + b_proj --------
__global__ __launch_bounds__(256) void k_proj(const float* __restrict__ x,
                                              const float* __restrict__ wproj,
                                              const float* __restrict__ bproj,
                                              const float* __restrict__ ws,
                                              float* __restrict__ out) {
    int b = blockIdx.z, n0 = blockIdx.x * 128, m0 = blockIdx.y * 128;
    int t = threadIdx.x;
    __shared__ float As[32][132];
    __shared__ float Bs[32][132];
    float acc[8][8];
#pragma unroll
    for (int i = 0; i < 8; ++i)
#pragma unroll
        for (int j = 0; j < 8; ++j) acc[i][j] = 0.f;
    int tm = t >> 4, tn = t & 15;

    for (int k0 = 0; k0 < CDIM; k0 += 32) {
        {
            int kk = (t & 7) * 4;
            int rbase = t >> 3;
#pragma unroll
            for (int p = 0; p < 4; ++p) {
                int row = p * 32 + rbase;
                float4 a4 = *reinterpret_cast<const float4*>(
                    wproj + (size_t)(m0 + row) * CDIM + k0 + kk);
                As[kk + 0][row] = a4.x; As[kk + 1][row] = a4.y;
                As[kk + 2][row] = a4.z; As[kk + 3][row] = a4.w;
            }
        }
        {
            int nf = (t & 31) * 4;
            int kb = t >> 5;
#pragma unroll
            for (int p = 0; p < 4; ++p) {
                int k = p * 8 + kb;
                int c = k0 + k;
                const float* src = (c < PD)
                    ? (ws + OFF_X1O + (size_t)b * PD * NPIX + (size_t)c * NPIX)
                    : (x + (size_t)b * CDIM * NPIX + (size_t)c * NPIX);
                float4 v4 = *reinterpret_cast<const float4*>(src + n0 + nf);
                // silu
                float4 o4;
                o4.x = v4.x / (1.f + __expf(-v4.x));
                o4.y = v4.y / (1.f + __expf(-v4.y));
                o4.z = v4.z / (1.f + __expf(-v4.z));
                o4.w = v4.w / (1.f + __expf(-v4.w));
                *reinterpret_cast<float4*>(&Bs[k][nf]) = o4;
            }
        }
        __syncthreads();
#pragma unroll 2
        for (int k = 0; k < 32; ++k) {
            float4 a0 = *reinterpret_cast<const float4*>(&As[k][tm * 8]);
            float4 a1 = *reinterpret_cast<const float4*>(&As[k][tm * 8 + 4]);
            float4 b0 = *reinterpret_cast<const float4*>(&Bs[k][tn * 8]);
            float4 b1 = *reinterpret_cast<const float4*>(&Bs[k][tn * 8 + 4]);
            float av[8] = {a0.x, a0.y, a0.z, a0.w, a1.x, a1.y, a1.z, a1.w};
            float bv[8] = {b0.x, b0.y, b0.z, b0.w, b1.x, b1.y, b1.z, b1.w};
#pragma unroll
            for (int i = 0; i < 8; ++i)
#pragma unroll
                for (int j = 0; j < 8; ++j) acc[i][j] += av[i] * bv[j];
        }
        __syncthreads();
    }
    float* ob = out + (size_t)b * CDIM * NPIX;
#pragma unroll
    for (int i = 0; i < 8; ++i) {
        int o = m0 + tm * 8 + i;
        float bb = bproj[o];
        float4 r0 = make_float4(acc[i][0] + bb, acc[i][1] + bb, acc[i][2] + bb, acc[i][3] + bb);
        float4 r1 = make_float4(acc[i][4] + bb, acc[i][5] + bb, acc[i][6] + bb, acc[i][7] + bb);
        *reinterpret_cast<float4*>(ob + (size_t)o * NPIX + n0 + tn * 8)     = r0;
        *reinterpret_cast<float4*>(ob + (size_t)o * NPIX + n0 + tn * 8 + 4) = r1;
    }
}

extern "C" void kernel_launch(void* const* d_in, const int* in_sizes, int n_in,
                              void* d_out, int out_size, void* d_ws, size_t ws_size,
                              hipStream_t stream) {
    const float* x     = (const float*)d_in[0];
    const float* gnw   = (const float*)d_in[1];
    const float* gnb   = (const float*)d_in[2];
    const float* wqkv  = (const float*)d_in[3];
    const float* bqkv  = (const float*)d_in[4];
    const float* wproj = (const float*)d_in[5];
    const float* bproj = (const float*)d_in[6];
    float* out = (float*)d_out;
    float* ws  = (float*)d_ws;

    k_stats_partial<<<dim3(64, 8), 256, 0, stream>>>(x, ws);
    k_stats_final<<<8, 64, 0, stream>>>(ws);
    k_qk<<<dim3(64, 8), 256, 0, stream>>>(x, gnw, gnb, wqkv, bqkv, ws);
    k_vgemm<<<dim3(32, 2, 8), 256, 0, stream>>>(x, gnw, gnb, wqkv, bqkv, ws);
    k_attn_stats<<<dim3(64, 8), 256, 0, stream>>>(ws);
    k_attn_pv<<<dim3(32, 8), 512, 0, stream>>>(ws);
    k_proj<<<dim3(32, 4, 8), 256, 0, stream>>>(x, wproj, bproj, ws, out);
}

// Round 2
// 572.877 us; speedup vs baseline: 2.6323x; 2.6323x over previous
//
#include <hip/hip_runtime.h>
#include <math.h>

typedef unsigned short u16;
typedef unsigned int u32;
typedef __attribute__((ext_vector_type(4))) u16 u16x4;
typedef __attribute__((ext_vector_type(8))) short bf16x8;
typedef __attribute__((ext_vector_type(4))) float f32x4;

#define MFMA16(a, b, c) __builtin_amdgcn_mfma_f32_16x16x32_bf16(a, b, c, 0, 0, 0)

namespace {
constexpr int BATCH = 8;
constexpr int CDIM  = 512;
constexpr int PD    = 256;
constexpr int NPIX  = 4096;
constexpr int NTOT  = PD * NPIX;

// fp32 workspace region (float offsets)
constexpr int OFF_PART = 0;       // 8*64*2
constexpr int OFF_STAT = 2048;    // 8*2
constexpr int OFF_M    = 4096;    // 8*4096
constexpr int OFF_L    = 36864;   // 8*4096  (floats end at 69632)

// bf16 regions (u16 offsets from ws base)
constexpr size_t U16_BASE = 139264;                     // byte 278528
constexpr size_t QT_ELEMS = (size_t)BATCH * NPIX * 16;  // 524288
constexpr size_t V_ELEMS  = (size_t)BATCH * PD * NPIX;  // 8388608
constexpr size_t Y_ELEMS  = (size_t)BATCH * NPIX * CDIM;// 16777216
} // namespace

__device__ __forceinline__ u16 f2bf(float f) {
    union { float f; u32 u; } v; v.f = f;
    return (u16)((v.u + 0x7fffu + ((v.u >> 16) & 1u)) >> 16);
}
__device__ __forceinline__ float bf2f(u16 h) {
    union { u32 u; float f; } v; v.u = ((u32)h) << 16;
    return v.f;
}

// ---------------- K1a: per-chunk partial sums for GroupNorm stats ----------
__global__ __launch_bounds__(256) void k_stats_partial(const float* __restrict__ x,
                                                       float* __restrict__ ws) {
    int b = blockIdx.y, chunk = blockIdx.x, t = threadIdx.x;
    const float4* x4 = reinterpret_cast<const float4*>(
        x + (size_t)b * CDIM * NPIX + (size_t)chunk * 16384);
    float s = 0.f, sq = 0.f;
#pragma unroll
    for (int i = 0; i < 16; ++i) {
        float4 v = x4[i * 256 + t];
        s  += v.x + v.y + v.z + v.w;
        sq += v.x * v.x + v.y * v.y + v.z * v.z + v.w * v.w;
    }
    for (int off = 32; off; off >>= 1) {
        s  += __shfl_down(s, off);
        sq += __shfl_down(sq, off);
    }
    __shared__ float red[8];
    int wid = t >> 6, lane = t & 63;
    if (lane == 0) { red[wid * 2] = s; red[wid * 2 + 1] = sq; }
    __syncthreads();
    if (t == 0) {
        float S = red[0] + red[2] + red[4] + red[6];
        float Q = red[1] + red[3] + red[5] + red[7];
        ws[OFF_PART + (b * 64 + chunk) * 2]     = S;
        ws[OFF_PART + (b * 64 + chunk) * 2 + 1] = Q;
    }
}

__global__ __launch_bounds__(64) void k_stats_final(float* __restrict__ ws) {
    int b = blockIdx.x, t = threadIdx.x;
    float s = ws[OFF_PART + (b * 64 + t) * 2];
    float q = ws[OFF_PART + (b * 64 + t) * 2 + 1];
    for (int off = 32; off; off >>= 1) {
        s += __shfl_down(s, off);
        q += __shfl_down(q, off);
    }
    if (t == 0) {
        float mean = s / (float)NTOT;
        float var  = q / (float)NTOT - mean * mean;
        ws[OFF_STAT + b * 2]     = mean;
        ws[OFF_STAT + b * 2 + 1] = rsqrtf(var + 1e-5f);
    }
}

// ---------------- K2a: q,k -> transposed bf16 (scale baked into q) ---------
__global__ __launch_bounds__(256) void k_qk_bf16(const float* __restrict__ x,
        const float* __restrict__ gnw, const float* __restrict__ gnb,
        const float* __restrict__ wqkv, const float* __restrict__ bqkv,
        const float* __restrict__ wsf, u16* __restrict__ qt, u16* __restrict__ kt) {
    int b = blockIdx.y, n0 = blockIdx.x * 64, t = threadIdx.x;
    int o = t & 31, ng = t >> 5;
    float mu = wsf[OFF_STAT + b * 2], rs = wsf[OFF_STAT + b * 2 + 1];
    const float* xb = x + (size_t)b * CDIM * NPIX;
    float acc[8];
    float bias = bqkv[o];
#pragma unroll
    for (int i = 0; i < 8; ++i) acc[i] = bias;
    for (int c = 0; c < PD; ++c) {
        float w = wqkv[o * PD + c];
        float a = rs * gnw[c];
        float sh = gnb[c] - mu * a;
        const float* xr = xb + (size_t)c * NPIX + n0;
#pragma unroll
        for (int i = 0; i < 8; ++i) {
            float xv = xr[ng + 8 * i];
            acc[i] += w * (xv * a + sh);
        }
    }
    float sc = (o < 16) ? 0.25f : 1.0f;
    u16* dst = (o < 16) ? (qt + (size_t)b * NPIX * 16 + o)
                        : (kt + (size_t)b * NPIX * 16 + (o - 16));
#pragma unroll
    for (int i = 0; i < 8; ++i) dst[(size_t)(n0 + ng + 8 * i) * 16] = f2bf(acc[i] * sc);
}

// ---------------- K2b: v = w_v @ x1n + b_v, bf16 out [b][c][n] -------------
__global__ __launch_bounds__(256) void k_vgemm_bf16(const float* __restrict__ x,
        const float* __restrict__ gnw, const float* __restrict__ gnb,
        const float* __restrict__ wqkv, const float* __restrict__ bqkv,
        const float* __restrict__ wsf, u16* __restrict__ vb) {
    int b = blockIdx.z, n0 = blockIdx.x * 128, m0 = blockIdx.y * 128;
    int t = threadIdx.x;
    float mu = wsf[OFF_STAT + b * 2], rs = wsf[OFF_STAT + b * 2 + 1];
    __shared__ float As[32][132];
    __shared__ float Bs[32][132];
    float acc[8][8];
#pragma unroll
    for (int i = 0; i < 8; ++i)
#pragma unroll
        for (int j = 0; j < 8; ++j) acc[i][j] = 0.f;
    const float* xb = x + (size_t)b * CDIM * NPIX;
    int tm = t >> 4, tn = t & 15;

    for (int k0 = 0; k0 < PD; k0 += 32) {
        {
            int kk = (t & 7) * 4;
            int rbase = t >> 3;
#pragma unroll
            for (int p = 0; p < 4; ++p) {
                int row = p * 32 + rbase;
                float4 a4 = *reinterpret_cast<const float4*>(
                    wqkv + (size_t)(32 + m0 + row) * PD + k0 + kk);
                As[kk + 0][row] = a4.x; As[kk + 1][row] = a4.y;
                As[kk + 2][row] = a4.z; As[kk + 3][row] = a4.w;
            }
        }
        {
            int nf = (t & 31) * 4;
            int kb = t >> 5;
#pragma unroll
            for (int p = 0; p < 4; ++p) {
                int k = p * 8 + kb;
                int c = k0 + k;
                float a = rs * gnw[c];
                float sh = gnb[c] - mu * a;
                float4 v4 = *reinterpret_cast<const float4*>(xb + (size_t)c * NPIX + n0 + nf);
                float4 o4 = make_float4(v4.x * a + sh, v4.y * a + sh,
                                        v4.z * a + sh, v4.w * a + sh);
                *reinterpret_cast<float4*>(&Bs[k][nf]) = o4;
            }
        }
        __syncthreads();
#pragma unroll 2
        for (int k = 0; k < 32; ++k) {
            float4 a0 = *reinterpret_cast<const float4*>(&As[k][tm * 8]);
            float4 a1 = *reinterpret_cast<const float4*>(&As[k][tm * 8 + 4]);
            float4 b0 = *reinterpret_cast<const float4*>(&Bs[k][tn * 8]);
            float4 b1 = *reinterpret_cast<const float4*>(&Bs[k][tn * 8 + 4]);
            float av[8] = {a0.x, a0.y, a0.z, a0.w, a1.x, a1.y, a1.z, a1.w};
            float bv[8] = {b0.x, b0.y, b0.z, b0.w, b1.x, b1.y, b1.z, b1.w};
#pragma unroll
            for (int i = 0; i < 8; ++i)
#pragma unroll
                for (int j = 0; j < 8; ++j) acc[i][j] += av[i] * bv[j];
        }
        __syncthreads();
    }
    u16* vout = vb + (size_t)b * PD * NPIX;
#pragma unroll
    for (int i = 0; i < 8; ++i) {
        int c = m0 + tm * 8 + i;
        float bb = bqkv[32 + c];
        u16x4 r0, r1;
        r0.x = f2bf(acc[i][0] + bb); r0.y = f2bf(acc[i][1] + bb);
        r0.z = f2bf(acc[i][2] + bb); r0.w = f2bf(acc[i][3] + bb);
        r1.x = f2bf(acc[i][4] + bb); r1.y = f2bf(acc[i][5] + bb);
        r1.z = f2bf(acc[i][6] + bb); r1.w = f2bf(acc[i][7] + bb);
        *reinterpret_cast<u16x4*>(vout + (size_t)c * NPIX + n0 + tn * 8)     = r0;
        *reinterpret_cast<u16x4*>(vout + (size_t)c * NPIX + n0 + tn * 8 + 4) = r1;
    }
}

// ---------------- K3a: softmax M,L from bf16 q,k ---------------------------
__global__ __launch_bounds__(256) void k_attn_ml(const u16* __restrict__ qt,
        const u16* __restrict__ kt, float* __restrict__ wsf) {
    int b = blockIdx.y, q0 = blockIdx.x * 64, t = threadIdx.x;
    __shared__ float Ql[64][17];
    __shared__ float Kl[64][17];
    const u16* qb = qt + ((size_t)b * NPIX + q0) * 16;
    const u16* kb = kt + (size_t)b * NPIX * 16;
    {
        int r = t >> 2, d4 = (t & 3) * 4;
        u16x4 u = *reinterpret_cast<const u16x4*>(qb + r * 16 + d4);
        Ql[r][d4 + 0] = bf2f(u.x); Ql[r][d4 + 1] = bf2f(u.y);
        Ql[r][d4 + 2] = bf2f(u.z); Ql[r][d4 + 3] = bf2f(u.w);
    }
    int nq = t >> 2, g = t & 3;
    float mrun = -1e30f, lrun = 0.f;
    for (int m0 = 0; m0 < NPIX; m0 += 64) {
        __syncthreads();
        {
            int r = t >> 2, d4 = (t & 3) * 4;
            u16x4 u = *reinterpret_cast<const u16x4*>(kb + (size_t)(m0 + r) * 16 + d4);
            Kl[r][d4 + 0] = bf2f(u.x); Kl[r][d4 + 1] = bf2f(u.y);
            Kl[r][d4 + 2] = bf2f(u.z); Kl[r][d4 + 3] = bf2f(u.w);
        }
        __syncthreads();
        float s[16];
#pragma unroll
        for (int j = 0; j < 16; ++j) s[j] = 0.f;
#pragma unroll
        for (int d = 0; d < 16; ++d) {
            float qd = Ql[nq][d];
#pragma unroll
            for (int j = 0; j < 16; ++j) s[j] += qd * Kl[g * 16 + j][d];
        }
        float tmax = -1e30f;
#pragma unroll
        for (int j = 0; j < 16; ++j) tmax = fmaxf(tmax, s[j]);
        float mnew = fmaxf(mrun, tmax);
        float sum = 0.f;
#pragma unroll
        for (int j = 0; j < 16; ++j) sum += __expf(s[j] - mnew);
        lrun = lrun * __expf(mrun - mnew) + sum;
        mrun = mnew;
    }
#pragma unroll
    for (int off = 1; off <= 2; off <<= 1) {
        float mo = __shfl_xor(mrun, off);
        float lo = __shfl_xor(lrun, off);
        float mnew = fmaxf(mrun, mo);
        lrun = lrun * __expf(mrun - mnew) + lo * __expf(mo - mnew);
        mrun = mnew;
    }
    if (g == 0) {
        wsf[OFF_M + b * NPIX + q0 + nq] = mrun;
        wsf[OFF_L + b * NPIX + q0 + nq] = lrun;
    }
}

// ---------------- K3b: fused flash PV with MFMA ----------------------------
// grid 256 blocks (b = bid&7 -> XCD-local V), 512 threads = 8 waves.
// Output tile: 256c x 128n; wave w owns c in [w*32, w*32+32), all 128 n.
__global__ __launch_bounds__(512) void k_attn_pv(const u16* __restrict__ qt,
        const u16* __restrict__ kt, const u16* __restrict__ vb,
        const float* __restrict__ wsf, u16* __restrict__ yb) {
    int bid = blockIdx.x;
    int b = bid & 7, q0 = (bid >> 3) * 128;
    int t = threadIdx.x, w = t >> 6, l = t & 63, lg = l >> 4, lr = l & 15;
    __shared__ u16 Pl[2][8192]; // [dbuf][n*64+m], XOR-swizzled

    const u16* Qt = qt + ((size_t)b * NPIX + q0) * 16;
    const u16* Kt = kt + (size_t)b * NPIX * 16;
    const u16* Vb = vb + (size_t)b * PD * NPIX;
    const float* Mp = wsf + OFF_M + b * NPIX + q0;
    const float* Lp = wsf + OFF_L + b * NPIX + q0;

    // loop-invariant operands
    bf16x8 qf = {0, 0, 0, 0, 0, 0, 0, 0};
    if (lg < 2) qf = *reinterpret_cast<const bf16x8*>(Qt + (w * 16 + lr) * 16 + lg * 8);
    float Ms[4];
#pragma unroll
    for (int r = 0; r < 4; ++r) Ms[r] = Mp[w * 16 + 4 * lg + r];
    float invl[8];
#pragma unroll
    for (int nf = 0; nf < 8; ++nf) invl[nf] = 1.f / Lp[nf * 16 + lr];

    const f32x4 z4 = {0.f, 0.f, 0.f, 0.f};
    f32x4 acc[2][8];
#pragma unroll
    for (int cf = 0; cf < 2; ++cf)
#pragma unroll
        for (int nf = 0; nf < 8; ++nf) acc[cf][nf] = z4;

    int cur = 0;
    for (int m0 = 0; m0 < NPIX; m0 += 64, cur ^= 1) {
        // --- scores for this wave's 16-query band (K padded 16->32) ---
#pragma unroll
        for (int mf = 0; mf < 4; ++mf) {
            bf16x8 kf = {0, 0, 0, 0, 0, 0, 0, 0};
            if (lg < 2)
                kf = *reinterpret_cast<const bf16x8*>(
                    Kt + (size_t)(m0 + mf * 16 + lr) * 16 + lg * 8);
            f32x4 s = MFMA16(qf, kf, z4);
#pragma unroll
            for (int r = 0; r < 4; ++r) {
                float p = __expf(s[r] - Ms[r]); // scale baked into q
                int n = w * 16 + 4 * lg + r;
                int m = mf * 16 + lr;
                Pl[cur][(n * 64 + m) ^ ((n & 7) << 3)] = f2bf(p);
            }
        }
        __syncthreads();
        // --- PV: acc[c][n] += V[c][m] * P[n][m] ---
#pragma unroll
        for (int ks = 0; ks < 2; ++ks) {
            bf16x8 vf0 = *reinterpret_cast<const bf16x8*>(
                Vb + (size_t)(w * 32 + lr) * NPIX + m0 + ks * 32 + lg * 8);
            bf16x8 vf1 = *reinterpret_cast<const bf16x8*>(
                Vb + (size_t)(w * 32 + 16 + lr) * NPIX + m0 + ks * 32 + lg * 8);
#pragma unroll
            for (int nf = 0; nf < 8; ++nf) {
                int n = nf * 16 + lr;
                bf16x8 pf = *reinterpret_cast<const bf16x8*>(
                    &Pl[cur][(n * 64 + ks * 32 + lg * 8) ^ ((n & 7) << 3)]);
                acc[0][nf] = MFMA16(vf0, pf, acc[0][nf]);
                acc[1][nf] = MFMA16(vf1, pf, acc[1][nf]);
            }
        }
    }
    // --- epilogue: /L, SiLU, write y transposed [b][n][c] bf16 ---
    u16* yrow = yb + (size_t)b * NPIX * CDIM;
#pragma unroll
    for (int nf = 0; nf < 8; ++nf) {
#pragma unroll
        for (int cf = 0; cf < 2; ++cf) {
#pragma unroll
            for (int r = 0; r < 4; ++r) {
                float v = acc[cf][nf][r] * invl[nf];
                float sv = v / (1.f + __expf(-v));
                int n = q0 + nf * 16 + lr;
                int c = w * 32 + cf * 16 + 4 * lg + r;
                yrow[(size_t)n * CDIM + c] = f2bf(sv);
            }
        }
    }
}

// ---------------- K5: silu(x2) -> yb[b][n][256+c] bf16 ---------------------
__global__ __launch_bounds__(256) void k_silu2(const float* __restrict__ x,
                                               u16* __restrict__ yb) {
    int b = blockIdx.z, c0 = blockIdx.y * 64, n0 = blockIdx.x * 64, t = threadIdx.x;
    __shared__ u16 T[64][72];
    const float* xb = x + ((size_t)b * CDIM + PD + c0) * NPIX;
    int c = t >> 2, nb = (t & 3) * 16;
#pragma unroll
    for (int j = 0; j < 4; ++j) {
        float4 v = *reinterpret_cast<const float4*>(xb + (size_t)c * NPIX + n0 + nb + j * 4);
        T[nb + j * 4 + 0][c] = f2bf(v.x / (1.f + __expf(-v.x)));
        T[nb + j * 4 + 1][c] = f2bf(v.y / (1.f + __expf(-v.y)));
        T[nb + j * 4 + 2][c] = f2bf(v.z / (1.f + __expf(-v.z)));
        T[nb + j * 4 + 3][c] = f2bf(v.w / (1.f + __expf(-v.w)));
    }
    __syncthreads();
    int n = t >> 2, cb = (t & 3) * 16;
    u16* dst = yb + ((size_t)b * NPIX + n0 + n) * CDIM + PD + c0 + cb;
#pragma unroll
    for (int j = 0; j < 4; ++j)
        *reinterpret_cast<u16x4*>(dst + j * 4) = *reinterpret_cast<u16x4*>(&T[n][cb + j * 4]);
}

// ---------------- K6: w_proj -> bf16 ---------------------------------------
__global__ __launch_bounds__(256) void k_cvt_w(const float* __restrict__ w,
                                               u16* __restrict__ wb) {
    int i = (blockIdx.x * 256 + threadIdx.x) * 4;
    float4 v = *reinterpret_cast<const float4*>(w + i);
    u16x4 o;
    o.x = f2bf(v.x); o.y = f2bf(v.y); o.z = f2bf(v.z); o.w = f2bf(v.w);
    *reinterpret_cast<u16x4*>(wb + i) = o;
}

// ---------------- K7: out = w_proj_bf16 @ y_bf16 + b_proj (MFMA) -----------
__global__ __launch_bounds__(256) void k_proj_mfma(const u16* __restrict__ wb,
        const u16* __restrict__ yb, const float* __restrict__ bproj,
        float* __restrict__ out) {
    int b = blockIdx.z, n0 = blockIdx.x * 128, o0 = blockIdx.y * 128;
    int t = threadIdx.x, w = t >> 6, l = t & 63, lg = l >> 4, lr = l & 15;
    int wo = w & 1, wn = w >> 1;
    int obase = o0 + wo * 64, nbase = n0 + wn * 64;
    const u16* ybb = yb + (size_t)b * NPIX * CDIM;
    const f32x4 z4 = {0.f, 0.f, 0.f, 0.f};
    f32x4 acc[4][4];
#pragma unroll
    for (int i = 0; i < 4; ++i)
#pragma unroll
        for (int j = 0; j < 4; ++j) acc[i][j] = z4;

    for (int k0 = 0; k0 < CDIM; k0 += 32) {
        bf16x8 af[4], bfr[4];
#pragma unroll
        for (int of = 0; of < 4; ++of)
            af[of] = *reinterpret_cast<const bf16x8*>(
                wb + (size_t)(obase + of * 16 + lr) * CDIM + k0 + lg * 8);
#pragma unroll
        for (int nf = 0; nf < 4; ++nf)
            bfr[nf] = *reinterpret_cast<const bf16x8*>(
                ybb + (size_t)(nbase + nf * 16 + lr) * CDIM + k0 + lg * 8);
#pragma unroll
        for (int of = 0; of < 4; ++of)
#pragma unroll
            for (int nf = 0; nf < 4; ++nf)
                acc[of][nf] = MFMA16(af[of], bfr[nf], acc[of][nf]);
    }
#pragma unroll
    for (int of = 0; of < 4; ++of) {
        int o = obase + of * 16 + 4 * lg;
#pragma unroll
        for (int r = 0; r < 4; ++r) {
            float bb = bproj[o + r];
#pragma unroll
            for (int nf = 0; nf < 4; ++nf)
                out[((size_t)b * CDIM + o + r) * NPIX + nbase + nf * 16 + lr] =
                    acc[of][nf][r] + bb;
        }
    }
}

extern "C" void kernel_launch(void* const* d_in, const int* in_sizes, int n_in,
                              void* d_out, int out_size, void* d_ws, size_t ws_size,
                              hipStream_t stream) {
    const float* x     = (const float*)d_in[0];
    const float* gnw   = (const float*)d_in[1];
    const float* gnb   = (const float*)d_in[2];
    const float* wqkv  = (const float*)d_in[3];
    const float* bqkv  = (const float*)d_in[4];
    const float* wproj = (const float*)d_in[5];
    const float* bproj = (const float*)d_in[6];
    float* out = (float*)d_out;
    float* wsf = (float*)d_ws;

    u16* qtp = (u16*)d_ws + U16_BASE;
    u16* ktp = qtp + QT_ELEMS;
    u16* vbp = ktp + QT_ELEMS;
    u16* ybp = vbp + V_ELEMS;
    u16* wbp = ybp + Y_ELEMS;

    k_stats_partial<<<dim3(64, 8), 256, 0, stream>>>(x, wsf);
    k_stats_final<<<8, 64, 0, stream>>>(wsf);
    k_cvt_w<<<256, 256, 0, stream>>>(wproj, wbp);
    k_silu2<<<dim3(64, 4, 8), 256, 0, stream>>>(x, ybp);
    k_qk_bf16<<<dim3(64, 8), 256, 0, stream>>>(x, gnw, gnb, wqkv, bqkv, wsf, qtp, ktp);
    k_vgemm_bf16<<<dim3(32, 2, 8), 256, 0, stream>>>(x, gnw, gnb, wqkv, bqkv, wsf, vbp);
    k_attn_ml<<<dim3(64, 8), 256, 0, stream>>>(qtp, ktp, wsf);
    k_attn_pv<<<256, 512, 0, stream>>>(qtp, ktp, vbp, wsf, ybp);
    k_proj_mfma<<<dim3(32, 4, 8), 256, 0, stream>>>(wbp, ybp, bproj, out);
}

// Round 3
// 382.350 us; speedup vs baseline: 3.9439x; 1.4983x over previous
//
#include <hip/hip_runtime.h>
#include <math.h>

typedef unsigned short u16;
typedef unsigned int u32;
typedef __attribute__((ext_vector_type(4))) u16 u16x4;
typedef __attribute__((ext_vector_type(8))) short bf16x8;
typedef __attribute__((ext_vector_type(4))) float f32x4;

#define MFMA16(a, b, c) __builtin_amdgcn_mfma_f32_16x16x32_bf16(a, b, c, 0, 0, 0)

namespace {
constexpr int BATCH = 8;
constexpr int CDIM  = 512;
constexpr int PD    = 256;
constexpr int NPIX  = 4096;
constexpr int NTOT  = PD * NPIX;

// fp32 workspace region (float offsets)
constexpr int OFF_PART = 0;       // 8*64*2
constexpr int OFF_STAT = 2048;    // 8*2

// bf16 regions (u16 offsets from ws base)
constexpr size_t U16_BASE = 139264;                     // byte 278528
constexpr size_t QT_ELEMS = (size_t)BATCH * NPIX * 16;  // 524288
constexpr size_t V_ELEMS  = (size_t)BATCH * PD * NPIX;  // 8388608
constexpr size_t Y_ELEMS  = (size_t)BATCH * NPIX * CDIM;// 16777216
} // namespace

__device__ __forceinline__ u16 f2bf(float f) {
    union { float f; u32 u; } v; v.f = f;
    return (u16)((v.u + 0x7fffu + ((v.u >> 16) & 1u)) >> 16);
}
__device__ __forceinline__ float bf2f(u16 h) {
    union { u32 u; float f; } v; v.u = ((u32)h) << 16;
    return v.f;
}

// ---------------- K1a: per-chunk partial sums for GroupNorm stats ----------
__global__ __launch_bounds__(256) void k_stats_partial(const float* __restrict__ x,
                                                       float* __restrict__ ws) {
    int b = blockIdx.y, chunk = blockIdx.x, t = threadIdx.x;
    const float4* x4 = reinterpret_cast<const float4*>(
        x + (size_t)b * CDIM * NPIX + (size_t)chunk * 16384);
    float s = 0.f, sq = 0.f;
#pragma unroll
    for (int i = 0; i < 16; ++i) {
        float4 v = x4[i * 256 + t];
        s  += v.x + v.y + v.z + v.w;
        sq += v.x * v.x + v.y * v.y + v.z * v.z + v.w * v.w;
    }
    for (int off = 32; off; off >>= 1) {
        s  += __shfl_down(s, off);
        sq += __shfl_down(sq, off);
    }
    __shared__ float red[8];
    int wid = t >> 6, lane = t & 63;
    if (lane == 0) { red[wid * 2] = s; red[wid * 2 + 1] = sq; }
    __syncthreads();
    if (t == 0) {
        float S = red[0] + red[2] + red[4] + red[6];
        float Q = red[1] + red[3] + red[5] + red[7];
        ws[OFF_PART + (b * 64 + chunk) * 2]     = S;
        ws[OFF_PART + (b * 64 + chunk) * 2 + 1] = Q;
    }
}

__global__ __launch_bounds__(64) void k_stats_final(float* __restrict__ ws) {
    int b = blockIdx.x, t = threadIdx.x;
    float s = ws[OFF_PART + (b * 64 + t) * 2];
    float q = ws[OFF_PART + (b * 64 + t) * 2 + 1];
    for (int off = 32; off; off >>= 1) {
        s += __shfl_down(s, off);
        q += __shfl_down(q, off);
    }
    if (t == 0) {
        float mean = s / (float)NTOT;
        float var  = q / (float)NTOT - mean * mean;
        ws[OFF_STAT + b * 2]     = mean;
        ws[OFF_STAT + b * 2 + 1] = rsqrtf(var + 1e-5f);
    }
}

// ---------------- K2a: q,k -> transposed bf16 (scale baked into q) ---------
__global__ __launch_bounds__(256) void k_qk_bf16(const float* __restrict__ x,
        const float* __restrict__ gnw, const float* __restrict__ gnb,
        const float* __restrict__ wqkv, const float* __restrict__ bqkv,
        const float* __restrict__ wsf, u16* __restrict__ qt, u16* __restrict__ kt) {
    int b = blockIdx.y, n0 = blockIdx.x * 64, t = threadIdx.x;
    int o = t & 31, ng = t >> 5;
    float mu = wsf[OFF_STAT + b * 2], rs = wsf[OFF_STAT + b * 2 + 1];
    const float* xb = x + (size_t)b * CDIM * NPIX;
    float acc[8];
    float bias = bqkv[o];
#pragma unroll
    for (int i = 0; i < 8; ++i) acc[i] = bias;
    for (int c = 0; c < PD; ++c) {
        float w = wqkv[o * PD + c];
        float a = rs * gnw[c];
        float sh = gnb[c] - mu * a;
        const float* xr = xb + (size_t)c * NPIX + n0;
#pragma unroll
        for (int i = 0; i < 8; ++i) {
            float xv = xr[ng + 8 * i];
            acc[i] += w * (xv * a + sh);
        }
    }
    float sc = (o < 16) ? 0.25f : 1.0f;
    u16* dst = (o < 16) ? (qt + (size_t)b * NPIX * 16 + o)
                        : (kt + (size_t)b * NPIX * 16 + (o - 16));
#pragma unroll
    for (int i = 0; i < 8; ++i) dst[(size_t)(n0 + ng + 8 * i) * 16] = f2bf(acc[i] * sc);
}

// ---------------- K2b: v = w_v @ x1n + b_v, bf16 out [b][c][n] -------------
__global__ __launch_bounds__(256) void k_vgemm_bf16(const float* __restrict__ x,
        const float* __restrict__ gnw, const float* __restrict__ gnb,
        const float* __restrict__ wqkv, const float* __restrict__ bqkv,
        const float* __restrict__ wsf, u16* __restrict__ vb) {
    int b = blockIdx.z, n0 = blockIdx.x * 128, m0 = blockIdx.y * 128;
    int t = threadIdx.x;
    float mu = wsf[OFF_STAT + b * 2], rs = wsf[OFF_STAT + b * 2 + 1];
    __shared__ float As[32][132];
    __shared__ float Bs[32][132];
    float acc[8][8];
#pragma unroll
    for (int i = 0; i < 8; ++i)
#pragma unroll
        for (int j = 0; j < 8; ++j) acc[i][j] = 0.f;
    const float* xb = x + (size_t)b * CDIM * NPIX;
    int tm = t >> 4, tn = t & 15;

    for (int k0 = 0; k0 < PD; k0 += 32) {
        {
            int kk = (t & 7) * 4;
            int rbase = t >> 3;
#pragma unroll
            for (int p = 0; p < 4; ++p) {
                int row = p * 32 + rbase;
                float4 a4 = *reinterpret_cast<const float4*>(
                    wqkv + (size_t)(32 + m0 + row) * PD + k0 + kk);
                As[kk + 0][row] = a4.x; As[kk + 1][row] = a4.y;
                As[kk + 2][row] = a4.z; As[kk + 3][row] = a4.w;
            }
        }
        {
            int nf = (t & 31) * 4;
            int kb = t >> 5;
#pragma unroll
            for (int p = 0; p < 4; ++p) {
                int k = p * 8 + kb;
                int c = k0 + k;
                float a = rs * gnw[c];
                float sh = gnb[c] - mu * a;
                float4 v4 = *reinterpret_cast<const float4*>(xb + (size_t)c * NPIX + n0 + nf);
                float4 o4 = make_float4(v4.x * a + sh, v4.y * a + sh,
                                        v4.z * a + sh, v4.w * a + sh);
                *reinterpret_cast<float4*>(&Bs[k][nf]) = o4;
            }
        }
        __syncthreads();
#pragma unroll 2
        for (int k = 0; k < 32; ++k) {
            float4 a0 = *reinterpret_cast<const float4*>(&As[k][tm * 8]);
            float4 a1 = *reinterpret_cast<const float4*>(&As[k][tm * 8 + 4]);
            float4 b0 = *reinterpret_cast<const float4*>(&Bs[k][tn * 8]);
            float4 b1 = *reinterpret_cast<const float4*>(&Bs[k][tn * 8 + 4]);
            float av[8] = {a0.x, a0.y, a0.z, a0.w, a1.x, a1.y, a1.z, a1.w};
            float bv[8] = {b0.x, b0.y, b0.z, b0.w, b1.x, b1.y, b1.z, b1.w};
#pragma unroll
            for (int i = 0; i < 8; ++i)
#pragma unroll
                for (int j = 0; j < 8; ++j) acc[i][j] += av[i] * bv[j];
        }
        __syncthreads();
    }
    u16* vout = vb + (size_t)b * PD * NPIX;
#pragma unroll
    for (int i = 0; i < 8; ++i) {
        int c = m0 + tm * 8 + i;
        float bb = bqkv[32 + c];
        u16x4 r0, r1;
        r0.x = f2bf(acc[i][0] + bb); r0.y = f2bf(acc[i][1] + bb);
        r0.z = f2bf(acc[i][2] + bb); r0.w = f2bf(acc[i][3] + bb);
        r1.x = f2bf(acc[i][4] + bb); r1.y = f2bf(acc[i][5] + bb);
        r1.z = f2bf(acc[i][6] + bb); r1.w = f2bf(acc[i][7] + bb);
        *reinterpret_cast<u16x4*>(vout + (size_t)c * NPIX + n0 + tn * 8)     = r0;
        *reinterpret_cast<u16x4*>(vout + (size_t)c * NPIX + n0 + tn * 8 + 4) = r1;
    }
}

// ---------------- K3: fully fused flash PV (no separate softmax pass) ------
// softmax computed as p=exp(s) (no max subtraction; scores ~N(0,1), guard at 60),
// L accumulated in-kernel. grid 256 blocks (b = bid&7 -> XCD-local V), 8 waves.
// Output tile: 256c x 128n; wave w owns c in [w*32, w*32+32), all 128 n.
__global__ __launch_bounds__(512) void k_attn_pv(const u16* __restrict__ qt,
        const u16* __restrict__ kt, const u16* __restrict__ vb,
        u16* __restrict__ yb) {
    int bid = blockIdx.x;
    int b = bid & 7, q0 = (bid >> 3) * 128;
    int t = threadIdx.x, w = t >> 6, l = t & 63, lg = l >> 4, lr = l & 15;
    __shared__ u16 Pl[2][8192]; // [dbuf][n*64+m], XOR-swizzled
    __shared__ float Ls[128];

    const u16* Qt = qt + ((size_t)b * NPIX + q0) * 16;
    const u16* Kt = kt + (size_t)b * NPIX * 16;
    const u16* Vb = vb + (size_t)b * PD * NPIX;

    // Q as B-operand fragment: B[k=d][col=lr] = Q[n=w*16+lr][d], d padded 16->32
    bf16x8 qf = {0, 0, 0, 0, 0, 0, 0, 0};
    if (lg < 2) qf = *reinterpret_cast<const bf16x8*>(Qt + (w * 16 + lr) * 16 + lg * 8);

    float lp = 0.f; // partial softmax denom for query n=w*16+lr (m-slice of this lane)

    const f32x4 z4 = {0.f, 0.f, 0.f, 0.f};
    f32x4 acc[2][8];
#pragma unroll
    for (int cf = 0; cf < 2; ++cf)
#pragma unroll
        for (int nf = 0; nf < 8; ++nf) acc[cf][nf] = z4;

    int cur = 0;
    for (int m0 = 0; m0 < NPIX; m0 += 64, cur ^= 1) {
        // --- scores for this wave's 16-query band, S^T = K·Q^T ---
        // D[row=m: mf*16+4lg+r][col=n: lr] -> 4 consecutive m per lane
#pragma unroll
        for (int mf = 0; mf < 4; ++mf) {
            bf16x8 kf = {0, 0, 0, 0, 0, 0, 0, 0};
            if (lg < 2)
                kf = *reinterpret_cast<const bf16x8*>(
                    Kt + (size_t)(m0 + mf * 16 + lr) * 16 + lg * 8);
            f32x4 s = MFMA16(kf, qf, z4);
            float p0 = __expf(fminf(s[0], 60.f));
            float p1 = __expf(fminf(s[1], 60.f));
            float p2 = __expf(fminf(s[2], 60.f));
            float p3 = __expf(fminf(s[3], 60.f));
            lp += (p0 + p1) + (p2 + p3);
            u16x4 pw;
            pw.x = f2bf(p0); pw.y = f2bf(p1); pw.z = f2bf(p2); pw.w = f2bf(p3);
            int nfull = w * 16 + lr;
            int mloc = mf * 16 + 4 * lg;
            *reinterpret_cast<u16x4*>(
                &Pl[cur][(nfull * 64 + mloc) ^ ((nfull & 7) << 3)]) = pw;
        }
        __syncthreads();
        // --- PV: acc[c][n] += V[c][m] * P[n][m] ---
#pragma unroll
        for (int ks = 0; ks < 2; ++ks) {
            bf16x8 vf0 = *reinterpret_cast<const bf16x8*>(
                Vb + (size_t)(w * 32 + lr) * NPIX + m0 + ks * 32 + lg * 8);
            bf16x8 vf1 = *reinterpret_cast<const bf16x8*>(
                Vb + (size_t)(w * 32 + 16 + lr) * NPIX + m0 + ks * 32 + lg * 8);
#pragma unroll
            for (int nf = 0; nf < 8; ++nf) {
                int n = nf * 16 + lr;
                bf16x8 pf = *reinterpret_cast<const bf16x8*>(
                    &Pl[cur][(n * 64 + ks * 32 + lg * 8) ^ ((n & 7) << 3)]);
                acc[0][nf] = MFMA16(vf0, pf, acc[0][nf]);
                acc[1][nf] = MFMA16(vf1, pf, acc[1][nf]);
            }
        }
    }
    // --- finalize L: sum partials across the 4 lg groups (same lr) ---
    lp += __shfl_xor(lp, 16);
    lp += __shfl_xor(lp, 32);
    if (l < 16) Ls[w * 16 + l] = lp;
    __syncthreads();
    // --- epilogue: /L, SiLU, write y transposed [b][n][c] bf16 ---
    float invl[8];
#pragma unroll
    for (int nf = 0; nf < 8; ++nf) invl[nf] = 1.f / Ls[nf * 16 + lr];
    u16* yrow = yb + (size_t)b * NPIX * CDIM;
#pragma unroll
    for (int nf = 0; nf < 8; ++nf) {
#pragma unroll
        for (int cf = 0; cf < 2; ++cf) {
#pragma unroll
            for (int r = 0; r < 4; ++r) {
                float v = acc[cf][nf][r] * invl[nf];
                float sv = v / (1.f + __expf(-v));
                int n = q0 + nf * 16 + lr;
                int c = w * 32 + cf * 16 + 4 * lg + r;
                yrow[(size_t)n * CDIM + c] = f2bf(sv);
            }
        }
    }
}

// ---------------- K5: silu(x2) -> yb[b][n][256+c] bf16 ---------------------
__global__ __launch_bounds__(256) void k_silu2(const float* __restrict__ x,
                                               u16* __restrict__ yb) {
    int b = blockIdx.z, c0 = blockIdx.y * 64, n0 = blockIdx.x * 64, t = threadIdx.x;
    __shared__ u16 T[64][72];
    const float* xb = x + ((size_t)b * CDIM + PD + c0) * NPIX;
    int c = t >> 2, nb = (t & 3) * 16;
#pragma unroll
    for (int j = 0; j < 4; ++j) {
        float4 v = *reinterpret_cast<const float4*>(xb + (size_t)c * NPIX + n0 + nb + j * 4);
        T[nb + j * 4 + 0][c] = f2bf(v.x / (1.f + __expf(-v.x)));
        T[nb + j * 4 + 1][c] = f2bf(v.y / (1.f + __expf(-v.y)));
        T[nb + j * 4 + 2][c] = f2bf(v.z / (1.f + __expf(-v.z)));
        T[nb + j * 4 + 3][c] = f2bf(v.w / (1.f + __expf(-v.w)));
    }
    __syncthreads();
    int n = t >> 2, cb = (t & 3) * 16;
    u16* dst = yb + ((size_t)b * NPIX + n0 + n) * CDIM + PD + c0 + cb;
#pragma unroll
    for (int j = 0; j < 4; ++j)
        *reinterpret_cast<u16x4*>(dst + j * 4) = *reinterpret_cast<u16x4*>(&T[n][cb + j * 4]);
}

// ---------------- K6: w_proj -> bf16 ---------------------------------------
__global__ __launch_bounds__(256) void k_cvt_w(const float* __restrict__ w,
                                               u16* __restrict__ wb) {
    int i = (blockIdx.x * 256 + threadIdx.x) * 4;
    float4 v = *reinterpret_cast<const float4*>(w + i);
    u16x4 o;
    o.x = f2bf(v.x); o.y = f2bf(v.y); o.z = f2bf(v.z); o.w = f2bf(v.w);
    *reinterpret_cast<u16x4*>(wb + i) = o;
}

// ---------------- K7: out = w_proj_bf16 @ y_bf16 + b_proj (MFMA) -----------
__global__ __launch_bounds__(256) void k_proj_mfma(const u16* __restrict__ wb,
        const u16* __restrict__ yb, const float* __restrict__ bproj,
        float* __restrict__ out) {
    int b = blockIdx.z, n0 = blockIdx.x * 128, o0 = blockIdx.y * 128;
    int t = threadIdx.x, w = t >> 6, l = t & 63, lg = l >> 4, lr = l & 15;
    int wo = w & 1, wn = w >> 1;
    int obase = o0 + wo * 64, nbase = n0 + wn * 64;
    const u16* ybb = yb + (size_t)b * NPIX * CDIM;
    const f32x4 z4 = {0.f, 0.f, 0.f, 0.f};
    f32x4 acc[4][4];
#pragma unroll
    for (int i = 0; i < 4; ++i)
#pragma unroll
        for (int j = 0; j < 4; ++j) acc[i][j] = z4;

    for (int k0 = 0; k0 < CDIM; k0 += 32) {
        bf16x8 af[4], bfr[4];
#pragma unroll
        for (int of = 0; of < 4; ++of)
            af[of] = *reinterpret_cast<const bf16x8*>(
                wb + (size_t)(obase + of * 16 + lr) * CDIM + k0 + lg * 8);
#pragma unroll
        for (int nf = 0; nf < 4; ++nf)
            bfr[nf] = *reinterpret_cast<const bf16x8*>(
                ybb + (size_t)(nbase + nf * 16 + lr) * CDIM + k0 + lg * 8);
#pragma unroll
        for (int of = 0; of < 4; ++of)
#pragma unroll
            for (int nf = 0; nf < 4; ++nf)
                acc[of][nf] = MFMA16(af[of], bfr[nf], acc[of][nf]);
    }
#pragma unroll
    for (int of = 0; of < 4; ++of) {
        int o = obase + of * 16 + 4 * lg;
#pragma unroll
        for (int r = 0; r < 4; ++r) {
            float bb = bproj[o + r];
#pragma unroll
            for (int nf = 0; nf < 4; ++nf)
                out[((size_t)b * CDIM + o + r) * NPIX + nbase + nf * 16 + lr] =
                    acc[of][nf][r] + bb;
        }
    }
}

extern "C" void kernel_launch(void* const* d_in, const int* in_sizes, int n_in,
                              void* d_out, int out_size, void* d_ws, size_t ws_size,
                              hipStream_t stream) {
    const float* x     = (const float*)d_in[0];
    const float* gnw   = (const float*)d_in[1];
    const float* gnb   = (const float*)d_in[2];
    const float* wqkv  = (const float*)d_in[3];
    const float* bqkv  = (const float*)d_in[4];
    const float* wproj = (const float*)d_in[5];
    const float* bproj = (const float*)d_in[6];
    float* out = (float*)d_out;
    float* wsf = (float*)d_ws;

    u16* qtp = (u16*)d_ws + U16_BASE;
    u16* ktp = qtp + QT_ELEMS;
    u16* vbp = ktp + QT_ELEMS;
    u16* ybp = vbp + V_ELEMS;
    u16* wbp = ybp + Y_ELEMS;

    k_stats_partial<<<dim3(64, 8), 256, 0, stream>>>(x, wsf);
    k_stats_final<<<8, 64, 0, stream>>>(wsf);
    k_cvt_w<<<256, 256, 0, stream>>>(wproj, wbp);
    k_silu2<<<dim3(64, 4, 8), 256, 0, stream>>>(x, ybp);
    k_qk_bf16<<<dim3(64, 8), 256, 0, stream>>>(x, gnw, gnb, wqkv, bqkv, wsf, qtp, ktp);
    k_vgemm_bf16<<<dim3(32, 2, 8), 256, 0, stream>>>(x, gnw, gnb, wqkv, bqkv, wsf, vbp);
    k_attn_pv<<<256, 512, 0, stream>>>(qtp, ktp, vbp, ybp);
    k_proj_mfma<<<dim3(32, 4, 8), 256, 0, stream>>>(wbp, ybp, bproj, out);
}

// Round 4
// 319.148 us; speedup vs baseline: 4.7250x; 1.1980x over previous
//
#include <hip/hip_runtime.h>
#include <math.h>

typedef unsigned short u16;
typedef unsigned int u32;
typedef __attribute__((ext_vector_type(4))) u16 u16x4;
typedef __attribute__((ext_vector_type(8))) short bf16x8;
typedef __attribute__((ext_vector_type(4))) float f32x4;

#define MFMA16(a, b, c) __builtin_amdgcn_mfma_f32_16x16x32_bf16(a, b, c, 0, 0, 0)

namespace {
constexpr int BATCH = 8;
constexpr int CDIM  = 512;
constexpr int PD    = 256;
constexpr int NPIX  = 4096;
constexpr int NTOT  = PD * NPIX;

// fp32 workspace region (float offsets)
constexpr int OFF_PART = 0;       // 8*64*2
constexpr int OFF_STAT = 2048;    // 8*2

// bf16 regions (u16 offsets from ws base)
constexpr size_t U16_BASE = 139264;                      // byte 278528
constexpr size_t QT_ELEMS = (size_t)BATCH * NPIX * 16;   // 524288
constexpr size_t V_ELEMS  = (size_t)BATCH * PD * NPIX;   // 8388608
constexpr size_t Y_ELEMS  = (size_t)BATCH * NPIX * CDIM; // 16777216
constexpr size_t WP_ELEMS = (size_t)CDIM * CDIM;         // 262144
constexpr size_t WQ_ELEMS = 288 * 256;                   // 73728
} // namespace

__device__ __forceinline__ u16 f2bf(float f) {
    union { float f; u32 u; } v; v.f = f;
    return (u16)((v.u + 0x7fffu + ((v.u >> 16) & 1u)) >> 16);
}

// ---------------- K1a: per-chunk partial sums for GroupNorm stats ----------
__global__ __launch_bounds__(256) void k_stats_partial(const float* __restrict__ x,
                                                       float* __restrict__ ws) {
    int b = blockIdx.y, chunk = blockIdx.x, t = threadIdx.x;
    const float4* x4 = reinterpret_cast<const float4*>(
        x + (size_t)b * CDIM * NPIX + (size_t)chunk * 16384);
    float s = 0.f, sq = 0.f;
#pragma unroll
    for (int i = 0; i < 16; ++i) {
        float4 v = x4[i * 256 + t];
        s  += v.x + v.y + v.z + v.w;
        sq += v.x * v.x + v.y * v.y + v.z * v.z + v.w * v.w;
    }
    for (int off = 32; off; off >>= 1) {
        s  += __shfl_down(s, off);
        sq += __shfl_down(sq, off);
    }
    __shared__ float red[8];
    int wid = t >> 6, lane = t & 63;
    if (lane == 0) { red[wid * 2] = s; red[wid * 2 + 1] = sq; }
    __syncthreads();
    if (t == 0) {
        float S = red[0] + red[2] + red[4] + red[6];
        float Q = red[1] + red[3] + red[5] + red[7];
        ws[OFF_PART + (b * 64 + chunk) * 2]     = S;
        ws[OFF_PART + (b * 64 + chunk) * 2 + 1] = Q;
    }
}

__global__ __launch_bounds__(64) void k_stats_final(float* __restrict__ ws) {
    int b = blockIdx.x, t = threadIdx.x;
    float s = ws[OFF_PART + (b * 64 + t) * 2];
    float q = ws[OFF_PART + (b * 64 + t) * 2 + 1];
    for (int off = 32; off; off >>= 1) {
        s += __shfl_down(s, off);
        q += __shfl_down(q, off);
    }
    if (t == 0) {
        float mean = s / (float)NTOT;
        float var  = q / (float)NTOT - mean * mean;
        ws[OFF_STAT + b * 2]     = mean;
        ws[OFF_STAT + b * 2 + 1] = rsqrtf(var + 1e-5f);
    }
}

// ---------------- generic fp32 -> bf16 convert -----------------------------
__global__ __launch_bounds__(256) void k_cvt(const float* __restrict__ src,
                                             u16* __restrict__ dst) {
    int i = (blockIdx.x * 256 + threadIdx.x) * 4;
    float4 v = *reinterpret_cast<const float4*>(src + i);
    u16x4 o;
    o.x = f2bf(v.x); o.y = f2bf(v.y); o.z = f2bf(v.z); o.w = f2bf(v.w);
    *reinterpret_cast<u16x4*>(dst + i) = o;
}

// ---------------- K2: xn = GroupNorm(x1) -> bf16 transposed [b][n][c] ------
__global__ __launch_bounds__(256) void k_xn(const float* __restrict__ x,
        const float* __restrict__ gnw, const float* __restrict__ gnb,
        const float* __restrict__ wsf, u16* __restrict__ xn) {
    int b = blockIdx.z, c0 = blockIdx.y * 64, n0 = blockIdx.x * 64, t = threadIdx.x;
    __shared__ u16 T[64][72];
    float mu = wsf[OFF_STAT + b * 2], rs = wsf[OFF_STAT + b * 2 + 1];
    int c = t >> 2, nb = (t & 3) * 16;
    int ca = c0 + c;
    float a = rs * gnw[ca];
    float sh = gnb[ca] - mu * a;
    const float* xb = x + ((size_t)b * CDIM + ca) * NPIX;
#pragma unroll
    for (int j = 0; j < 4; ++j) {
        float4 v = *reinterpret_cast<const float4*>(xb + n0 + nb + j * 4);
        T[nb + j * 4 + 0][c] = f2bf(v.x * a + sh);
        T[nb + j * 4 + 1][c] = f2bf(v.y * a + sh);
        T[nb + j * 4 + 2][c] = f2bf(v.z * a + sh);
        T[nb + j * 4 + 3][c] = f2bf(v.w * a + sh);
    }
    __syncthreads();
    int n = t >> 2, cb = (t & 3) * 16;
    u16* dst = xn + ((size_t)b * NPIX + n0 + n) * PD + c0 + cb;
#pragma unroll
    for (int j = 0; j < 4; ++j)
        *reinterpret_cast<u16x4*>(dst + j * 4) = *reinterpret_cast<u16x4*>(&T[n][cb + j * 4]);
}

// ---------------- K3: qkv = w_qkv_bf16 @ xn (MFMA) -------------------------
// D[row=n][col=o] = sum_c xn[n][c] * w[o][c].  o-tile 0 -> q,k; tiles 1..8 -> v.
__global__ __launch_bounds__(256) void k_qkv(const u16* __restrict__ xn,
        const u16* __restrict__ wq, const float* __restrict__ bqkv,
        u16* __restrict__ qt, u16* __restrict__ kt, u16* __restrict__ vb) {
    int b = blockIdx.z, o0 = blockIdx.y * 32, n0 = blockIdx.x * 256;
    int t = threadIdx.x, w = t >> 6, l = t & 63, lg = l >> 4, lr = l & 15;
    int nbase = n0 + w * 64;
    const u16* xnb = xn + (size_t)b * NPIX * PD;
    const f32x4 z4 = {0.f, 0.f, 0.f, 0.f};
    f32x4 acc[2][4];
#pragma unroll
    for (int i = 0; i < 2; ++i)
#pragma unroll
        for (int j = 0; j < 4; ++j) acc[i][j] = z4;

#pragma unroll
    for (int k0 = 0; k0 < PD; k0 += 32) {
        bf16x8 xf[4], wf[2];
#pragma unroll
        for (int nf = 0; nf < 4; ++nf)
            xf[nf] = *reinterpret_cast<const bf16x8*>(
                xnb + (size_t)(nbase + nf * 16 + lr) * PD + k0 + lg * 8);
#pragma unroll
        for (int of = 0; of < 2; ++of)
            wf[of] = *reinterpret_cast<const bf16x8*>(
                wq + (size_t)(o0 + of * 16 + lr) * PD + k0 + lg * 8);
#pragma unroll
        for (int of = 0; of < 2; ++of)
#pragma unroll
            for (int nf = 0; nf < 4; ++nf)
                acc[of][nf] = MFMA16(xf[nf], wf[of], acc[of][nf]);
    }

    if (o0 == 0) {
        // q rows (of=0, o=lr, scale 0.25) and k rows (of=1)
#pragma unroll
        for (int of = 0; of < 2; ++of) {
            int o = of * 16 + lr;
            float bias = bqkv[o];
            float sc = (of == 0) ? 0.25f : 1.0f;
            u16* dst = (of == 0) ? (qt + (size_t)b * NPIX * 16 + lr)
                                 : (kt + (size_t)b * NPIX * 16 + lr);
#pragma unroll
            for (int nf = 0; nf < 4; ++nf) {
#pragma unroll
                for (int r = 0; r < 4; ++r) {
                    int n = nbase + nf * 16 + 4 * lg + r;
                    dst[(size_t)n * 16] = f2bf((acc[of][nf][r] + bias) * sc);
                }
            }
        }
    } else {
        u16* vout = vb + (size_t)b * PD * NPIX;
#pragma unroll
        for (int of = 0; of < 2; ++of) {
            int c = o0 - 32 + of * 16 + lr;
            float bias = bqkv[32 + c];
#pragma unroll
            for (int nf = 0; nf < 4; ++nf) {
                u16x4 pw;
                pw.x = f2bf(acc[of][nf][0] + bias);
                pw.y = f2bf(acc[of][nf][1] + bias);
                pw.z = f2bf(acc[of][nf][2] + bias);
                pw.w = f2bf(acc[of][nf][3] + bias);
                *reinterpret_cast<u16x4*>(
                    vout + (size_t)c * NPIX + nbase + nf * 16 + 4 * lg) = pw;
            }
        }
    }
}

// ---------------- K4: fused flash PV (no max-subtraction softmax) ----------
// grid 1024: b=bid&7 (XCD-local V), q-tile 64, c-half 128. 4 waves.
// wave w: scores for n-band w*16; PV for c-band cbase+w*32 (2 c-frags).
__global__ __launch_bounds__(256) void k_attn_pv(const u16* __restrict__ qt,
        const u16* __restrict__ kt, const u16* __restrict__ vb,
        u16* __restrict__ yb) {
    int bid = blockIdx.x;
    int b = bid & 7, r2 = bid >> 3;
    int q0 = (r2 & 63) * 64, cbase = (r2 >> 6) * 128;
    int t = threadIdx.x, w = t >> 6, l = t & 63, lg = l >> 4, lr = l & 15;
    __shared__ u16 Pl[2][4096]; // [dbuf][n*64+m], XOR-swizzled, 64n x 64m
    __shared__ float Ls[64];

    const u16* Qt = qt + ((size_t)b * NPIX + q0) * 16;
    const u16* Kt = kt + (size_t)b * NPIX * 16;
    const u16* Vb = vb + (size_t)b * PD * NPIX;

    bf16x8 qf = {0, 0, 0, 0, 0, 0, 0, 0};
    if (lg < 2) qf = *reinterpret_cast<const bf16x8*>(Qt + (w * 16 + lr) * 16 + lg * 8);

    float lp = 0.f;
    const f32x4 z4 = {0.f, 0.f, 0.f, 0.f};
    f32x4 acc[2][4];
#pragma unroll
    for (int cf = 0; cf < 2; ++cf)
#pragma unroll
        for (int nf = 0; nf < 4; ++nf) acc[cf][nf] = z4;

    int cur = 0;
    for (int m0 = 0; m0 < NPIX; m0 += 64, cur ^= 1) {
        // scores S^T = K·Q^T for this wave's 16-query band
#pragma unroll
        for (int mf = 0; mf < 4; ++mf) {
            bf16x8 kf = {0, 0, 0, 0, 0, 0, 0, 0};
            if (lg < 2)
                kf = *reinterpret_cast<const bf16x8*>(
                    Kt + (size_t)(m0 + mf * 16 + lr) * 16 + lg * 8);
            f32x4 s = MFMA16(kf, qf, z4);
            float p0 = __expf(fminf(s[0], 60.f));
            float p1 = __expf(fminf(s[1], 60.f));
            float p2 = __expf(fminf(s[2], 60.f));
            float p3 = __expf(fminf(s[3], 60.f));
            lp += (p0 + p1) + (p2 + p3);
            u16x4 pw;
            pw.x = f2bf(p0); pw.y = f2bf(p1); pw.z = f2bf(p2); pw.w = f2bf(p3);
            int nfull = w * 16 + lr;
            int mloc = mf * 16 + 4 * lg;
            *reinterpret_cast<u16x4*>(
                &Pl[cur][(nfull * 64 + mloc) ^ ((nfull & 7) << 3)]) = pw;
        }
        __syncthreads();
        // PV: acc[c][n] += V[c][m] * P[n][m]
#pragma unroll
        for (int ks = 0; ks < 2; ++ks) {
            bf16x8 vf0 = *reinterpret_cast<const bf16x8*>(
                Vb + (size_t)(cbase + w * 32 + lr) * NPIX + m0 + ks * 32 + lg * 8);
            bf16x8 vf1 = *reinterpret_cast<const bf16x8*>(
                Vb + (size_t)(cbase + w * 32 + 16 + lr) * NPIX + m0 + ks * 32 + lg * 8);
#pragma unroll
            for (int nf = 0; nf < 4; ++nf) {
                int n = nf * 16 + lr;
                bf16x8 pf = *reinterpret_cast<const bf16x8*>(
                    &Pl[cur][(n * 64 + ks * 32 + lg * 8) ^ ((n & 7) << 3)]);
                acc[0][nf] = MFMA16(vf0, pf, acc[0][nf]);
                acc[1][nf] = MFMA16(vf1, pf, acc[1][nf]);
            }
        }
    }
    // finalize L across the 4 lg groups (same lr)
    lp += __shfl_xor(lp, 16);
    lp += __shfl_xor(lp, 32);
    if (l < 16) Ls[w * 16 + l] = lp;
    __syncthreads();
    float invl[4];
#pragma unroll
    for (int nf = 0; nf < 4; ++nf) invl[nf] = 1.f / Ls[nf * 16 + lr];
    // epilogue: /L, SiLU, write y transposed [b][n][c] bf16
    u16* yrow = yb + (size_t)b * NPIX * CDIM;
#pragma unroll
    for (int nf = 0; nf < 4; ++nf) {
        int n = q0 + nf * 16 + lr;
#pragma unroll
        for (int cf = 0; cf < 2; ++cf) {
            u16x4 pw;
#pragma unroll
            for (int r = 0; r < 4; ++r) {
                float v = acc[cf][nf][r] * invl[nf];
                pw[r] = f2bf(v / (1.f + __expf(-v)));
            }
            *reinterpret_cast<u16x4*>(
                yrow + (size_t)n * CDIM + cbase + w * 32 + cf * 16 + 4 * lg) = pw;
        }
    }
}

// ---------------- K5: silu(x2) -> yb[b][n][256+c] bf16 ---------------------
__global__ __launch_bounds__(256) void k_silu2(const float* __restrict__ x,
                                               u16* __restrict__ yb) {
    int b = blockIdx.z, c0 = blockIdx.y * 64, n0 = blockIdx.x * 64, t = threadIdx.x;
    __shared__ u16 T[64][72];
    const float* xb = x + ((size_t)b * CDIM + PD + c0) * NPIX;
    int c = t >> 2, nb = (t & 3) * 16;
#pragma unroll
    for (int j = 0; j < 4; ++j) {
        float4 v = *reinterpret_cast<const float4*>(xb + (size_t)c * NPIX + n0 + nb + j * 4);
        T[nb + j * 4 + 0][c] = f2bf(v.x / (1.f + __expf(-v.x)));
        T[nb + j * 4 + 1][c] = f2bf(v.y / (1.f + __expf(-v.y)));
        T[nb + j * 4 + 2][c] = f2bf(v.z / (1.f + __expf(-v.z)));
        T[nb + j * 4 + 3][c] = f2bf(v.w / (1.f + __expf(-v.w)));
    }
    __syncthreads();
    int n = t >> 2, cb = (t & 3) * 16;
    u16* dst = yb + ((size_t)b * NPIX + n0 + n) * CDIM + PD + c0 + cb;
#pragma unroll
    for (int j = 0; j < 4; ++j)
        *reinterpret_cast<u16x4*>(dst + j * 4) = *reinterpret_cast<u16x4*>(&T[n][cb + j * 4]);
}

// ---------------- K6: out = w_proj_bf16 @ y_bf16 + b_proj (MFMA) -----------
__global__ __launch_bounds__(256) void k_proj_mfma(const u16* __restrict__ wb,
        const u16* __restrict__ yb, const float* __restrict__ bproj,
        float* __restrict__ out) {
    int b = blockIdx.z, n0 = blockIdx.x * 128, o0 = blockIdx.y * 128;
    int t = threadIdx.x, w = t >> 6, l = t & 63, lg = l >> 4, lr = l & 15;
    int wo = w & 1, wn = w >> 1;
    int obase = o0 + wo * 64, nbase = n0 + wn * 64;
    const u16* ybb = yb + (size_t)b * NPIX * CDIM;
    const f32x4 z4 = {0.f, 0.f, 0.f, 0.f};
    f32x4 acc[4][4];
#pragma unroll
    for (int i = 0; i < 4; ++i)
#pragma unroll
        for (int j = 0; j < 4; ++j) acc[i][j] = z4;

    for (int k0 = 0; k0 < CDIM; k0 += 32) {
        bf16x8 af[4], bfr[4];
#pragma unroll
        for (int of = 0; of < 4; ++of)
            af[of] = *reinterpret_cast<const bf16x8*>(
                wb + (size_t)(obase + of * 16 + lr) * CDIM + k0 + lg * 8);
#pragma unroll
        for (int nf = 0; nf < 4; ++nf)
            bfr[nf] = *reinterpret_cast<const bf16x8*>(
                ybb + (size_t)(nbase + nf * 16 + lr) * CDIM + k0 + lg * 8);
#pragma unroll
        for (int of = 0; of < 4; ++of)
#pragma unroll
            for (int nf = 0; nf < 4; ++nf)
                acc[of][nf] = MFMA16(af[of], bfr[nf], acc[of][nf]);
    }
#pragma unroll
    for (int of = 0; of < 4; ++of) {
        int o = obase + of * 16 + 4 * lg;
#pragma unroll
        for (int r = 0; r < 4; ++r) {
            float bb = bproj[o + r];
#pragma unroll
            for (int nf = 0; nf < 4; ++nf)
                out[((size_t)b * CDIM + o + r) * NPIX + nbase + nf * 16 + lr] =
                    acc[of][nf][r] + bb;
        }
    }
}

extern "C" void kernel_launch(void* const* d_in, const int* in_sizes, int n_in,
                              void* d_out, int out_size, void* d_ws, size_t ws_size,
                              hipStream_t stream) {
    const float* x     = (const float*)d_in[0];
    const float* gnw   = (const float*)d_in[1];
    const float* gnb   = (const float*)d_in[2];
    const float* wqkv  = (const float*)d_in[3];
    const float* bqkv  = (const float*)d_in[4];
    const float* wproj = (const float*)d_in[5];
    const float* bproj = (const float*)d_in[6];
    float* out = (float*)d_out;
    float* wsf = (float*)d_ws;

    u16* qtp = (u16*)d_ws + U16_BASE;
    u16* ktp = qtp + QT_ELEMS;
    u16* vbp = ktp + QT_ELEMS;
    u16* ybp = vbp + V_ELEMS;
    u16* wbp = ybp + Y_ELEMS;
    u16* wqb = wbp + WP_ELEMS;
    u16* xnp = ybp; // xn aliases y: xn dead before silu2/pv write y (stream-ordered)

    k_stats_partial<<<dim3(64, 8), 256, 0, stream>>>(x, wsf);
    k_stats_final<<<8, 64, 0, stream>>>(wsf);
    k_cvt<<<256, 256, 0, stream>>>(wproj, wbp);
    k_cvt<<<72, 256, 0, stream>>>(wqkv, wqb);
    k_xn<<<dim3(64, 4, 8), 256, 0, stream>>>(x, gnw, gnb, wsf, xnp);
    k_qkv<<<dim3(16, 9, 8), 256, 0, stream>>>(xnp, wqb, bqkv, qtp, ktp, vbp);
    k_silu2<<<dim3(64, 4, 8), 256, 0, stream>>>(x, ybp);
    k_attn_pv<<<1024, 256, 0, stream>>>(qtp, ktp, vbp, ybp);
    k_proj_mfma<<<dim3(32, 4, 8), 256, 0, stream>>>(wbp, ybp, bproj, out);
}

// Round 5
// 308.880 us; speedup vs baseline: 4.8820x; 1.0332x over previous
//
#include <hip/hip_runtime.h>
#include <math.h>

typedef unsigned short u16;
typedef unsigned int u32;
typedef __attribute__((ext_vector_type(4))) u16 u16x4;
typedef __attribute__((ext_vector_type(8))) short bf16x8;
typedef __attribute__((ext_vector_type(4))) float f32x4;

#define MFMA16(a, b, c) __builtin_amdgcn_mfma_f32_16x16x32_bf16(a, b, c, 0, 0, 0)

namespace {
constexpr int BATCH = 8;
constexpr int CDIM  = 512;
constexpr int PD    = 256;
constexpr int NPIX  = 4096;
constexpr int NTOT  = PD * NPIX;
constexpr float LOG2E = 1.44269504088896f;

// fp32 workspace region (float offsets)
constexpr int OFF_PART = 0;       // 8*64*2
constexpr int OFF_STAT = 2048;    // 8*2

// bf16 regions (u16 offsets from ws base)
constexpr size_t U16_BASE = 139264;                      // byte 278528
constexpr size_t QT_ELEMS = (size_t)BATCH * NPIX * 16;   // 524288
constexpr size_t V_ELEMS  = (size_t)BATCH * PD * NPIX;   // 8388608
constexpr size_t Y_ELEMS  = (size_t)BATCH * NPIX * CDIM; // 16777216
constexpr size_t WP_ELEMS = (size_t)CDIM * CDIM;         // 262144
} // namespace

__device__ __forceinline__ u16 f2bf(float f) {
    union { float f; u32 u; } v; v.f = f;
    return (u16)((v.u + 0x7fffu + ((v.u >> 16) & 1u)) >> 16);
}
__device__ __forceinline__ u32 cvtpk(float lo, float hi) {
    u32 r;
    asm("v_cvt_pk_bf16_f32 %0, %1, %2" : "=v"(r) : "v"(lo), "v"(hi));
    return r;
}

// ---------------- K1a: per-chunk partial sums for GroupNorm stats ----------
__global__ __launch_bounds__(256) void k_stats_partial(const float* __restrict__ x,
                                                       float* __restrict__ ws) {
    int b = blockIdx.y, chunk = blockIdx.x, t = threadIdx.x;
    const float4* x4 = reinterpret_cast<const float4*>(
        x + (size_t)b * CDIM * NPIX + (size_t)chunk * 16384);
    float s = 0.f, sq = 0.f;
#pragma unroll
    for (int i = 0; i < 16; ++i) {
        float4 v = x4[i * 256 + t];
        s  += v.x + v.y + v.z + v.w;
        sq += v.x * v.x + v.y * v.y + v.z * v.z + v.w * v.w;
    }
    for (int off = 32; off; off >>= 1) {
        s  += __shfl_down(s, off);
        sq += __shfl_down(sq, off);
    }
    __shared__ float red[8];
    int wid = t >> 6, lane = t & 63;
    if (lane == 0) { red[wid * 2] = s; red[wid * 2 + 1] = sq; }
    __syncthreads();
    if (t == 0) {
        float S = red[0] + red[2] + red[4] + red[6];
        float Q = red[1] + red[3] + red[5] + red[7];
        ws[OFF_PART + (b * 64 + chunk) * 2]     = S;
        ws[OFF_PART + (b * 64 + chunk) * 2 + 1] = Q;
    }
}

__global__ __launch_bounds__(64) void k_stats_final(float* __restrict__ ws) {
    int b = blockIdx.x, t = threadIdx.x;
    float s = ws[OFF_PART + (b * 64 + t) * 2];
    float q = ws[OFF_PART + (b * 64 + t) * 2 + 1];
    for (int off = 32; off; off >>= 1) {
        s += __shfl_down(s, off);
        q += __shfl_down(q, off);
    }
    if (t == 0) {
        float mean = s / (float)NTOT;
        float var  = q / (float)NTOT - mean * mean;
        ws[OFF_STAT + b * 2]     = mean;
        ws[OFF_STAT + b * 2 + 1] = rsqrtf(var + 1e-5f);
    }
}

// ---------------- generic fp32 -> bf16 convert -----------------------------
__global__ __launch_bounds__(256) void k_cvt(const float* __restrict__ src,
                                             u16* __restrict__ dst) {
    int i = (blockIdx.x * 256 + threadIdx.x) * 4;
    float4 v = *reinterpret_cast<const float4*>(src + i);
    u16x4 o;
    o.x = f2bf(v.x); o.y = f2bf(v.y); o.z = f2bf(v.z); o.w = f2bf(v.w);
    *reinterpret_cast<u16x4*>(dst + i) = o;
}

// ---------------- K2: xn = GroupNorm(x1) -> bf16 transposed [b][n][c] ------
__global__ __launch_bounds__(256) void k_xn(const float* __restrict__ x,
        const float* __restrict__ gnw, const float* __restrict__ gnb,
        const float* __restrict__ wsf, u16* __restrict__ xn) {
    int b = blockIdx.z, c0 = blockIdx.y * 64, n0 = blockIdx.x * 64, t = threadIdx.x;
    __shared__ u16 T[64][72];
    float mu = wsf[OFF_STAT + b * 2], rs = wsf[OFF_STAT + b * 2 + 1];
    int c = t >> 2, nb = (t & 3) * 16;
    int ca = c0 + c;
    float a = rs * gnw[ca];
    float sh = gnb[ca] - mu * a;
    const float* xb = x + ((size_t)b * CDIM + ca) * NPIX;
#pragma unroll
    for (int j = 0; j < 4; ++j) {
        float4 v = *reinterpret_cast<const float4*>(xb + n0 + nb + j * 4);
        T[nb + j * 4 + 0][c] = f2bf(v.x * a + sh);
        T[nb + j * 4 + 1][c] = f2bf(v.y * a + sh);
        T[nb + j * 4 + 2][c] = f2bf(v.z * a + sh);
        T[nb + j * 4 + 3][c] = f2bf(v.w * a + sh);
    }
    __syncthreads();
    int n = t >> 2, cb = (t & 3) * 16;
    u16* dst = xn + ((size_t)b * NPIX + n0 + n) * PD + c0 + cb;
#pragma unroll
    for (int j = 0; j < 4; ++j)
        *reinterpret_cast<u16x4*>(dst + j * 4) = *reinterpret_cast<u16x4*>(&T[n][cb + j * 4]);
}

// ---------------- K3: qkv = w_qkv_bf16 @ xn (MFMA) -------------------------
// D[row=n][col=o] = sum_c xn[n][c] * w[o][c].  o-tile 0 -> q,k; tiles 1..8 -> v.
// q gets 0.25*log2(e) baked in so attention can use exp2 directly.
__global__ __launch_bounds__(256) void k_qkv(const u16* __restrict__ xn,
        const u16* __restrict__ wq, const float* __restrict__ bqkv,
        u16* __restrict__ qt, u16* __restrict__ kt, u16* __restrict__ vb) {
    int b = blockIdx.z, o0 = blockIdx.y * 32, n0 = blockIdx.x * 256;
    int t = threadIdx.x, w = t >> 6, l = t & 63, lg = l >> 4, lr = l & 15;
    int nbase = n0 + w * 64;
    const u16* xnb = xn + (size_t)b * NPIX * PD;
    const f32x4 z4 = {0.f, 0.f, 0.f, 0.f};
    f32x4 acc[2][4];
#pragma unroll
    for (int i = 0; i < 2; ++i)
#pragma unroll
        for (int j = 0; j < 4; ++j) acc[i][j] = z4;

#pragma unroll
    for (int k0 = 0; k0 < PD; k0 += 32) {
        bf16x8 xf[4], wf[2];
#pragma unroll
        for (int nf = 0; nf < 4; ++nf)
            xf[nf] = *reinterpret_cast<const bf16x8*>(
                xnb + (size_t)(nbase + nf * 16 + lr) * PD + k0 + lg * 8);
#pragma unroll
        for (int of = 0; of < 2; ++of)
            wf[of] = *reinterpret_cast<const bf16x8*>(
                wq + (size_t)(o0 + of * 16 + lr) * PD + k0 + lg * 8);
#pragma unroll
        for (int of = 0; of < 2; ++of)
#pragma unroll
            for (int nf = 0; nf < 4; ++nf)
                acc[of][nf] = MFMA16(xf[nf], wf[of], acc[of][nf]);
    }

    if (o0 == 0) {
        // q rows (of=0, scale 0.25*log2e) and k rows (of=1)
#pragma unroll
        for (int of = 0; of < 2; ++of) {
            int o = of * 16 + lr;
            float bias = bqkv[o];
            float sc = (of == 0) ? 0.25f * LOG2E : 1.0f;
            u16* dst = (of == 0) ? (qt + (size_t)b * NPIX * 16 + lr)
                                 : (kt + (size_t)b * NPIX * 16 + lr);
#pragma unroll
            for (int nf = 0; nf < 4; ++nf) {
#pragma unroll
                for (int r = 0; r < 4; ++r) {
                    int n = nbase + nf * 16 + 4 * lg + r;
                    dst[(size_t)n * 16] = f2bf((acc[of][nf][r] + bias) * sc);
                }
            }
        }
    } else {
        u16* vout = vb + (size_t)b * PD * NPIX;
#pragma unroll
        for (int of = 0; of < 2; ++of) {
            int c = o0 - 32 + of * 16 + lr;
            float bias = bqkv[32 + c];
#pragma unroll
            for (int nf = 0; nf < 4; ++nf) {
                u16x4 pw;
                pw.x = f2bf(acc[of][nf][0] + bias);
                pw.y = f2bf(acc[of][nf][1] + bias);
                pw.z = f2bf(acc[of][nf][2] + bias);
                pw.w = f2bf(acc[of][nf][3] + bias);
                *reinterpret_cast<u16x4*>(
                    vout + (size_t)c * NPIX + nbase + nf * 16 + 4 * lg) = pw;
            }
        }
    }
}

// ---------------- K4: fused flash PV ---------------------------------------
// grid 512: b=bid&7 (XCD-local K/V in L2), q-tile 64. 8 waves, no duplication:
// scores: 16 MFMAs/tile (4 n-bands x 4 mf) spread 2-per-wave;
// PV: wave w owns c-stripe [w*32, w*32+32) x all 64 n.
// p = exp2(s) with log2e baked into q; no max subtraction (scores ~N(0,1)).
__global__ __launch_bounds__(512) void k_attn_pv(const u16* __restrict__ qt,
        const u16* __restrict__ kt, const u16* __restrict__ vb,
        u16* __restrict__ yb) {
    int bid = blockIdx.x;
    int b = bid & 7, q0 = (bid >> 3) * 64;
    int t = threadIdx.x, w = t >> 6, l = t & 63, lg = l >> 4, lr = l & 15;
    int band = w & 3, mfb = w >> 2; // this wave scores n-band `band`, mf in {mfb, mfb+2}
    __shared__ u16 Pl[2][4096]; // [dbuf][n*64+m] u16, XOR-swizzled
    __shared__ float Ls[2][64];

    const u16* Qt = qt + ((size_t)b * NPIX + q0) * 16;
    const u16* Kt = kt + (size_t)b * NPIX * 16;
    const u16* Vb = vb + (size_t)b * PD * NPIX;

    // Q frag (B-operand) for this wave's score band: col n = band*16+lr
    bf16x8 qf = {0, 0, 0, 0, 0, 0, 0, 0};
    if (lg < 2)
        qf = *reinterpret_cast<const bf16x8*>(Qt + (band * 16 + lr) * 16 + lg * 8);

    float lp = 0.f;
    const f32x4 z4 = {0.f, 0.f, 0.f, 0.f};
    f32x4 acc[2][4];
#pragma unroll
    for (int cf = 0; cf < 2; ++cf)
#pragma unroll
        for (int nf = 0; nf < 4; ++nf) acc[cf][nf] = z4;

    int cur = 0;
    for (int m0 = 0; m0 < NPIX; m0 += 64, cur ^= 1) {
        // ---- scores S^T = K·Q^T: this wave's 2 (band, mf) fragments ----
#pragma unroll
        for (int i = 0; i < 2; ++i) {
            int mf = mfb + 2 * i;
            bf16x8 kf = {0, 0, 0, 0, 0, 0, 0, 0};
            if (lg < 2)
                kf = *reinterpret_cast<const bf16x8*>(
                    Kt + (size_t)(m0 + mf * 16 + lr) * 16 + lg * 8);
            f32x4 s = MFMA16(kf, qf, z4);
            // D[row=m: mf*16+4lg+r][col=n: band*16+lr]
            float p0 = exp2f(fminf(s[0], 80.f));
            float p1 = exp2f(fminf(s[1], 80.f));
            float p2 = exp2f(fminf(s[2], 80.f));
            float p3 = exp2f(fminf(s[3], 80.f));
            lp += (p0 + p1) + (p2 + p3);
            uint2 pw;
            pw.x = cvtpk(p0, p1);
            pw.y = cvtpk(p2, p3);
            int n = band * 16 + lr;
            int elem = n * 64 + mf * 16 + 4 * lg;
            *reinterpret_cast<uint2*>(&Pl[cur][elem ^ ((n & 7) << 3)]) = pw;
        }
        __syncthreads(); // P ready; prior reads drained (lgkmcnt before barrier)
        // ---- PV: acc[c][n] += V[c][m] * P[n][m] ----
#pragma unroll
        for (int ks = 0; ks < 2; ++ks) {
            bf16x8 vf0 = *reinterpret_cast<const bf16x8*>(
                Vb + (size_t)(w * 32 + lr) * NPIX + m0 + ks * 32 + lg * 8);
            bf16x8 vf1 = *reinterpret_cast<const bf16x8*>(
                Vb + (size_t)(w * 32 + 16 + lr) * NPIX + m0 + ks * 32 + lg * 8);
#pragma unroll
            for (int nf = 0; nf < 4; ++nf) {
                int n = nf * 16 + lr;
                bf16x8 pf = *reinterpret_cast<const bf16x8*>(
                    &Pl[cur][(n * 64 + ks * 32 + lg * 8) ^ ((n & 7) << 3)]);
                acc[0][nf] = MFMA16(vf0, pf, acc[0][nf]);
                acc[1][nf] = MFMA16(vf1, pf, acc[1][nf]);
            }
        }
    }
    // ---- finalize L: lane partial covers its (lg, mf-pair) m-slices ----
    lp += __shfl_xor(lp, 16);
    lp += __shfl_xor(lp, 32);
    if (l < 16) Ls[mfb][band * 16 + l] = lp; // waves w and w+4 hold complementary mf
    __syncthreads();
    float invl[4];
#pragma unroll
    for (int nf = 0; nf < 4; ++nf)
        invl[nf] = 1.f / (Ls[0][nf * 16 + lr] + Ls[1][nf * 16 + lr]);
    // ---- epilogue: /L, SiLU, write y transposed [b][n][c] bf16 ----
    u16* yrow = yb + (size_t)b * NPIX * CDIM;
#pragma unroll
    for (int nf = 0; nf < 4; ++nf) {
        int n = q0 + nf * 16 + lr;
#pragma unroll
        for (int cf = 0; cf < 2; ++cf) {
            u16x4 pw;
#pragma unroll
            for (int r = 0; r < 4; ++r) {
                float v = acc[cf][nf][r] * invl[nf];
                pw[r] = f2bf(v / (1.f + __expf(-v)));
            }
            *reinterpret_cast<u16x4*>(
                yrow + (size_t)n * CDIM + w * 32 + cf * 16 + 4 * lg) = pw;
        }
    }
}

// ---------------- K5: silu(x2) -> yb[b][n][256+c] bf16 ---------------------
__global__ __launch_bounds__(256) void k_silu2(const float* __restrict__ x,
                                               u16* __restrict__ yb) {
    int b = blockIdx.z, c0 = blockIdx.y * 64, n0 = blockIdx.x * 64, t = threadIdx.x;
    __shared__ u16 T[64][72];
    const float* xb = x + ((size_t)b * CDIM + PD + c0) * NPIX;
    int c = t >> 2, nb = (t & 3) * 16;
#pragma unroll
    for (int j = 0; j < 4; ++j) {
        float4 v = *reinterpret_cast<const float4*>(xb + (size_t)c * NPIX + n0 + nb + j * 4);
        T[nb + j * 4 + 0][c] = f2bf(v.x / (1.f + __expf(-v.x)));
        T[nb + j * 4 + 1][c] = f2bf(v.y / (1.f + __expf(-v.y)));
        T[nb + j * 4 + 2][c] = f2bf(v.z / (1.f + __expf(-v.z)));
        T[nb + j * 4 + 3][c] = f2bf(v.w / (1.f + __expf(-v.w)));
    }
    __syncthreads();
    int n = t >> 2, cb = (t & 3) * 16;
    u16* dst = yb + ((size_t)b * NPIX + n0 + n) * CDIM + PD + c0 + cb;
#pragma unroll
    for (int j = 0; j < 4; ++j)
        *reinterpret_cast<u16x4*>(dst + j * 4) = *reinterpret_cast<u16x4*>(&T[n][cb + j * 4]);
}

// ---------------- K6: out = w_proj_bf16 @ y_bf16 + b_proj (MFMA) -----------
__global__ __launch_bounds__(256) void k_proj_mfma(const u16* __restrict__ wb,
        const u16* __restrict__ yb, const float* __restrict__ bproj,
        float* __restrict__ out) {
    int b = blockIdx.z, n0 = blockIdx.x * 128, o0 = blockIdx.y * 128;
    int t = threadIdx.x, w = t >> 6, l = t & 63, lg = l >> 4, lr = l & 15;
    int wo = w & 1, wn = w >> 1;
    int obase = o0 + wo * 64, nbase = n0 + wn * 64;
    const u16* ybb = yb + (size_t)b * NPIX * CDIM;
    const f32x4 z4 = {0.f, 0.f, 0.f, 0.f};
    f32x4 acc[4][4];
#pragma unroll
    for (int i = 0; i < 4; ++i)
#pragma unroll
        for (int j = 0; j < 4; ++j) acc[i][j] = z4;

    for (int k0 = 0; k0 < CDIM; k0 += 32) {
        bf16x8 af[4], bfr[4];
#pragma unroll
        for (int of = 0; of < 4; ++of)
            af[of] = *reinterpret_cast<const bf16x8*>(
                wb + (size_t)(obase + of * 16 + lr) * CDIM + k0 + lg * 8);
#pragma unroll
        for (int nf = 0; nf < 4; ++nf)
            bfr[nf] = *reinterpret_cast<const bf16x8*>(
                ybb + (size_t)(nbase + nf * 16 + lr) * CDIM + k0 + lg * 8);
#pragma unroll
        for (int of = 0; of < 4; ++of)
#pragma unroll
            for (int nf = 0; nf < 4; ++nf)
                acc[of][nf] = MFMA16(af[of], bfr[nf], acc[of][nf]);
    }
#pragma unroll
    for (int of = 0; of < 4; ++of) {
        int o = obase + of * 16 + 4 * lg;
#pragma unroll
        for (int r = 0; r < 4; ++r) {
            float bb = bproj[o + r];
#pragma unroll
            for (int nf = 0; nf < 4; ++nf)
                out[((size_t)b * CDIM + o + r) * NPIX + nbase + nf * 16 + lr] =
                    acc[of][nf][r] + bb;
        }
    }
}

extern "C" void kernel_launch(void* const* d_in, const int* in_sizes, int n_in,
                              void* d_out, int out_size, void* d_ws, size_t ws_size,
                              hipStream_t stream) {
    const float* x     = (const float*)d_in[0];
    const float* gnw   = (const float*)d_in[1];
    const float* gnb   = (const float*)d_in[2];
    const float* wqkv  = (const float*)d_in[3];
    const float* bqkv  = (const float*)d_in[4];
    const float* wproj = (const float*)d_in[5];
    const float* bproj = (const float*)d_in[6];
    float* out = (float*)d_out;
    float* wsf = (float*)d_ws;

    u16* qtp = (u16*)d_ws + U16_BASE;
    u16* ktp = qtp + QT_ELEMS;
    u16* vbp = ktp + QT_ELEMS;
    u16* ybp = vbp + V_ELEMS;
    u16* wbp = ybp + Y_ELEMS;
    u16* wqb = wbp + WP_ELEMS;
    u16* xnp = ybp; // xn aliases y: xn dead before silu2/pv write y (stream-ordered)

    k_stats_partial<<<dim3(64, 8), 256, 0, stream>>>(x, wsf);
    k_stats_final<<<8, 64, 0, stream>>>(wsf);
    k_cvt<<<256, 256, 0, stream>>>(wproj, wbp);
    k_cvt<<<72, 256, 0, stream>>>(wqkv, wqb);
    k_xn<<<dim3(64, 4, 8), 256, 0, stream>>>(x, gnw, gnb, wsf, xnp);
    k_qkv<<<dim3(16, 9, 8), 256, 0, stream>>>(xnp, wqb, bqkv, qtp, ktp, vbp);
    k_silu2<<<dim3(64, 4, 8), 256, 0, stream>>>(x, ybp);
    k_attn_pv<<<512, 512, 0, stream>>>(qtp, ktp, vbp, ybp);
    k_proj_mfma<<<dim3(32, 4, 8), 256, 0, stream>>>(wbp, ybp, bproj, out);
}